// Round 1
// baseline (1900.538 us; speedup 1.0000x reference)
//
#include <hip/hip_runtime.h>
#include <hip/hip_bf16.h>

#define LR 0.01f
#define WD 0.01f

#define BM 128
#define BN 128
#define BK 8
#define TM 8
#define TN 8
#define NTHREADS 256

// ---------------------------------------------------------------------------
// Generic 128x128 fp32 tile GEMM bodies, epilogue-fused per kernel.
// Thread layout: 256 threads = 16x16, each owns an 8x8 micro-tile.
// ---------------------------------------------------------------------------

// K1: Tout = tanh(A @ B + bias)   A:[Md,Kd] rm, B:[Kd,Nd] rm
__global__ __launch_bounds__(NTHREADS)
void k_gemm_bias_tanh(const float* __restrict__ A, const float* __restrict__ B,
                      const float* __restrict__ bias, float* __restrict__ Tout,
                      int Md, int Nd, int Kd) {
    __shared__ float As[BK][BM];
    __shared__ float Bs[BK][BN];
    const int t = threadIdx.x;
    const int bn = blockIdx.x, bm = blockIdx.y;
    const int tx = t & 15, ty = t >> 4;
    float acc[TM][TN] = {};
    const int aRow = t >> 1, aCol = (t & 1) * 4;
    const int bRow = t >> 5, bCol = (t & 31) * 4;
    const float* Ab = A + (size_t)bm * BM * Kd;
    const float* Bb = B + bn * BN;
    for (int k0 = 0; k0 < Kd; k0 += BK) {
        float4 av = *(const float4*)(Ab + (size_t)aRow * Kd + k0 + aCol);
        float4 bv = *(const float4*)(Bb + (size_t)(k0 + bRow) * Nd + bCol);
        __syncthreads();
        As[aCol + 0][aRow] = av.x;
        As[aCol + 1][aRow] = av.y;
        As[aCol + 2][aRow] = av.z;
        As[aCol + 3][aRow] = av.w;
        *(float4*)&Bs[bRow][bCol] = bv;
        __syncthreads();
#pragma unroll
        for (int k = 0; k < BK; ++k) {
            float a[TM], b[TN];
#pragma unroll
            for (int i = 0; i < TM; ++i) a[i] = As[k][ty * TM + i];
#pragma unroll
            for (int j = 0; j < TN; ++j) b[j] = Bs[k][tx * TN + j];
#pragma unroll
            for (int i = 0; i < TM; ++i)
#pragma unroll
                for (int j = 0; j < TN; ++j) acc[i][j] = fmaf(a[i], b[j], acc[i][j]);
        }
    }
    const int r0 = bm * BM + ty * TM, c0 = bn * BN + tx * TN;
#pragma unroll
    for (int i = 0; i < TM; ++i)
#pragma unroll
        for (int j = 0; j < TN; ++j) {
            float c = acc[i][j] + bias[c0 + j];
            Tout[(size_t)(r0 + i) * Nd + c0 + j] = tanhf(c);
        }
}

// K2: pred = A @ B + bias ; h = pred ; G = scale*(pred - xtgt)
__global__ __launch_bounds__(NTHREADS)
void k_gemm_bias_out_grad(const float* __restrict__ A, const float* __restrict__ B,
                          const float* __restrict__ bias,
                          const float* __restrict__ xtgt,
                          float* __restrict__ h, float* __restrict__ G,
                          int Md, int Nd, int Kd, float scale) {
    __shared__ float As[BK][BM];
    __shared__ float Bs[BK][BN];
    const int t = threadIdx.x;
    const int bn = blockIdx.x, bm = blockIdx.y;
    const int tx = t & 15, ty = t >> 4;
    float acc[TM][TN] = {};
    const int aRow = t >> 1, aCol = (t & 1) * 4;
    const int bRow = t >> 5, bCol = (t & 31) * 4;
    const float* Ab = A + (size_t)bm * BM * Kd;
    const float* Bb = B + bn * BN;
    for (int k0 = 0; k0 < Kd; k0 += BK) {
        float4 av = *(const float4*)(Ab + (size_t)aRow * Kd + k0 + aCol);
        float4 bv = *(const float4*)(Bb + (size_t)(k0 + bRow) * Nd + bCol);
        __syncthreads();
        As[aCol + 0][aRow] = av.x;
        As[aCol + 1][aRow] = av.y;
        As[aCol + 2][aRow] = av.z;
        As[aCol + 3][aRow] = av.w;
        *(float4*)&Bs[bRow][bCol] = bv;
        __syncthreads();
#pragma unroll
        for (int k = 0; k < BK; ++k) {
            float a[TM], b[TN];
#pragma unroll
            for (int i = 0; i < TM; ++i) a[i] = As[k][ty * TM + i];
#pragma unroll
            for (int j = 0; j < TN; ++j) b[j] = Bs[k][tx * TN + j];
#pragma unroll
            for (int i = 0; i < TM; ++i)
#pragma unroll
                for (int j = 0; j < TN; ++j) acc[i][j] = fmaf(a[i], b[j], acc[i][j]);
        }
    }
    const int r0 = bm * BM + ty * TM, c0 = bn * BN + tx * TN;
#pragma unroll
    for (int i = 0; i < TM; ++i)
#pragma unroll
        for (int j = 0; j < TN; ++j) {
            float c = acc[i][j] + bias[c0 + j];
            size_t idx = (size_t)(r0 + i) * Nd + c0 + j;
            h[idx] = c;
            G[idx] = scale * (c - xtgt[idx]);
        }
}

// K3: dA = (G @ W^T) * (1 - T^2)   G:[Md,Kd] rm, W:[Nd,Kd] rm (w2), T:[Md,Nd]
__global__ __launch_bounds__(NTHREADS)
void k_gemm_bt_dact(const float* __restrict__ G, const float* __restrict__ W,
                    const float* __restrict__ Tin, float* __restrict__ dA,
                    int Md, int Nd, int Kd) {
    __shared__ float As[BK][BM];
    __shared__ float Bs[BK][BN];
    const int t = threadIdx.x;
    const int bn = blockIdx.x, bm = blockIdx.y;
    const int tx = t & 15, ty = t >> 4;
    float acc[TM][TN] = {};
    const int aRow = t >> 1, aCol = (t & 1) * 4;   // A-tile: 128 rows x 8 k
    const int wRow = t >> 1, wCol = (t & 1) * 4;   // W-tile: 128 n-rows x 8 k-cols
    const float* Ab = G + (size_t)bm * BM * Kd;
    const float* Wb = W + (size_t)bn * BN * Kd;
    for (int k0 = 0; k0 < Kd; k0 += BK) {
        float4 av = *(const float4*)(Ab + (size_t)aRow * Kd + k0 + aCol);
        float4 bv = *(const float4*)(Wb + (size_t)wRow * Kd + k0 + wCol);
        __syncthreads();
        As[aCol + 0][aRow] = av.x;
        As[aCol + 1][aRow] = av.y;
        As[aCol + 2][aRow] = av.z;
        As[aCol + 3][aRow] = av.w;
        Bs[wCol + 0][wRow] = bv.x;
        Bs[wCol + 1][wRow] = bv.y;
        Bs[wCol + 2][wRow] = bv.z;
        Bs[wCol + 3][wRow] = bv.w;
        __syncthreads();
#pragma unroll
        for (int k = 0; k < BK; ++k) {
            float a[TM], b[TN];
#pragma unroll
            for (int i = 0; i < TM; ++i) a[i] = As[k][ty * TM + i];
#pragma unroll
            for (int j = 0; j < TN; ++j) b[j] = Bs[k][tx * TN + j];
#pragma unroll
            for (int i = 0; i < TM; ++i)
#pragma unroll
                for (int j = 0; j < TN; ++j) acc[i][j] = fmaf(a[i], b[j], acc[i][j]);
        }
    }
    const int r0 = bm * BM + ty * TM, c0 = bn * BN + tx * TN;
#pragma unroll
    for (int i = 0; i < TM; ++i)
#pragma unroll
        for (int j = 0; j < TN; ++j) {
            size_t idx = (size_t)(r0 + i) * Nd + c0 + j;
            float tv = Tin[idx];
            dA[idx] = acc[i][j] * (1.0f - tv * tv);
        }
}

// K4/K5: C[m][n] += sum_l A[l][m]*B[l][n]  (A^T B), split-K over l with atomics
__global__ __launch_bounds__(NTHREADS)
void k_gemm_tn_atomic(const float* __restrict__ A, const float* __restrict__ B,
                      float* __restrict__ C, int Md, int Nd, int Lper) {
    __shared__ float As[BK][BM];
    __shared__ float Bs[BK][BN];
    const int t = threadIdx.x;
    const int bn = blockIdx.x, bm = blockIdx.y, bz = blockIdx.z;
    const int tx = t & 15, ty = t >> 4;
    float acc[TM][TN] = {};
    const int lRow = t >> 5;            // 0..7
    const int aCol = (t & 31) * 4;      // 0..124
    const int l0 = bz * Lper;
    for (int l = l0; l < l0 + Lper; l += BK) {
        float4 av = *(const float4*)(A + (size_t)(l + lRow) * Md + bm * BM + aCol);
        float4 bv = *(const float4*)(B + (size_t)(l + lRow) * Nd + bn * BN + aCol);
        __syncthreads();
        *(float4*)&As[lRow][aCol] = av;
        *(float4*)&Bs[lRow][aCol] = bv;
        __syncthreads();
#pragma unroll
        for (int k = 0; k < BK; ++k) {
            float a[TM], b[TN];
#pragma unroll
            for (int i = 0; i < TM; ++i) a[i] = As[k][ty * TM + i];
#pragma unroll
            for (int j = 0; j < TN; ++j) b[j] = Bs[k][tx * TN + j];
#pragma unroll
            for (int i = 0; i < TM; ++i)
#pragma unroll
                for (int j = 0; j < TN; ++j) acc[i][j] = fmaf(a[i], b[j], acc[i][j]);
        }
    }
    const int r0 = bm * BM + ty * TM, c0 = bn * BN + tx * TN;
#pragma unroll
    for (int i = 0; i < TM; ++i)
#pragma unroll
        for (int j = 0; j < TN; ++j)
            atomicAdd(&C[(size_t)(r0 + i) * Nd + c0 + j], acc[i][j]);
}

// column sum: dst[c] += sum over a row-chunk of src[r][c]
__global__ void k_colsum(const float* __restrict__ src, float* __restrict__ dst,
                         int C, int rowsPer) {
    int col = blockIdx.x * blockDim.x + threadIdx.x;
    int r0 = blockIdx.y * rowsPer;
    float s = 0.f;
    for (int r = r0; r < r0 + rowsPer; ++r) s += src[(size_t)r * C + col];
    atomicAdd(&dst[col], s);
}

// learned-optimizer elementwise update:
// out = p - (LR*(tanh(g*Wm1+bm1)@Wm2 + bm2) + WD*p)
__global__ void k_update(const float* __restrict__ p, const float* __restrict__ g,
                         float* __restrict__ out, int n,
                         const float* __restrict__ Wm1, const float* __restrict__ bm1,
                         const float* __restrict__ Wm2, const float* __restrict__ bm2,
                         int M) {
    __shared__ float s1[64], s2[64], s3[64];
    if (threadIdx.x < M) {
        s1[threadIdx.x] = Wm1[threadIdx.x];
        s2[threadIdx.x] = bm1[threadIdx.x];
        s3[threadIdx.x] = Wm2[threadIdx.x];
    }
    __syncthreads();
    int i = blockIdx.x * blockDim.x + threadIdx.x;
    if (i >= n) return;
    float gv = g[i];
    float u = bm2[0];
#pragma unroll 8
    for (int m = 0; m < M; ++m) u += tanhf(fmaf(gv, s1[m], s2[m])) * s3[m];
    float pv = p[i];
    out[i] = pv - (LR * u + WD * pv);
}

__global__ void k_zero(float* __restrict__ p, int n) {
    int i = blockIdx.x * blockDim.x + threadIdx.x;
    if (i < n) p[i] = 0.f;
}

extern "C" void kernel_launch(void* const* d_in, const int* in_sizes, int n_in,
                              void* d_out, int out_size, void* d_ws, size_t ws_size,
                              hipStream_t stream) {
    const float* x_t      = (const float*)d_in[0];
    const float* x_target = (const float*)d_in[1];
    const float* w1  = (const float*)d_in[2];
    const float* b1  = (const float*)d_in[3];
    const float* w2  = (const float*)d_in[4];
    const float* b2  = (const float*)d_in[5];
    const float* Wm1 = (const float*)d_in[6];
    const float* bm1 = (const float*)d_in[7];
    const float* Wm2 = (const float*)d_in[8];
    const float* bm2 = (const float*)d_in[9];

    const int H = in_sizes[3];          // b1 -> H = 1024
    const int D = in_sizes[5];          // b2 -> D = 512
    const int N = in_sizes[0] / D;      // 16384
    const int M = in_sizes[6];          // 32

    // workspace layout (fp32)
    float* T   = (float*)d_ws;                      // [N,H]
    float* G   = T   + (size_t)N * H;               // [N,D]
    float* dA  = G   + (size_t)N * D;               // [N,H]
    float* gw2 = dA  + (size_t)N * H;               // [H,D]
    float* gw1 = gw2 + (size_t)H * D;               // [D,H]
    float* gb1 = gw1 + (size_t)D * H;               // [H]
    float* gb2 = gb1 + H;                           // [D]

    float* out  = (float*)d_out;
    float* h_t  = out;                              // [N,D]
    float* o_w1 = h_t  + (size_t)N * D;             // [D,H]
    float* o_b1 = o_w1 + (size_t)D * H;             // [H]
    float* o_w2 = o_b1 + H;                         // [H,D]
    float* o_b2 = o_w2 + (size_t)H * D;             // [D]

    dim3 blk(NTHREADS);

    // zero the atomic-accumulated gradient region (gw2,gw1,gb1,gb2 contiguous)
    int zn = H * D + D * H + H + D;
    k_zero<<<dim3((zn + NTHREADS - 1) / NTHREADS), blk, 0, stream>>>(gw2, zn);

    // forward 1: T = tanh(x @ w1 + b1)       [N,H] = [N,D]x[D,H]
    k_gemm_bias_tanh<<<dim3(H / BN, N / BM), blk, 0, stream>>>(x_t, w1, b1, T, N, H, D);

    // forward 2 + grad wrt pred: h = T @ w2 + b2 ; G = 2*(h - x_target)/(N*D)
    float scale = 2.0f / ((float)N * (float)D);
    k_gemm_bias_out_grad<<<dim3(D / BN, N / BM), blk, 0, stream>>>(
        T, w2, b2, x_target, h_t, G, N, D, H, scale);

    // backward through tanh: dA = (G @ w2^T) * (1 - T^2)   [N,H]
    k_gemm_bt_dact<<<dim3(H / BN, N / BM), blk, 0, stream>>>(G, w2, T, dA, N, H, D);

    // grad_w2 = T^T @ G   [H,D], split-K=8 over N
    const int SPLIT = 8;
    k_gemm_tn_atomic<<<dim3(D / BN, H / BM, SPLIT), blk, 0, stream>>>(
        T, G, gw2, H, D, N / SPLIT);

    // grad_w1 = x^T @ dA  [D,H]
    k_gemm_tn_atomic<<<dim3(H / BN, D / BM, SPLIT), blk, 0, stream>>>(
        x_t, dA, gw1, D, H, N / SPLIT);

    // bias grads: column sums
    k_colsum<<<dim3(H / NTHREADS, 64), blk, 0, stream>>>(dA, gb1, H, N / 64);
    k_colsum<<<dim3(D / NTHREADS, 64), blk, 0, stream>>>(G, gb2, D, N / 64);

    // learned-optimizer updates
    k_update<<<dim3((D * H + NTHREADS - 1) / NTHREADS), blk, 0, stream>>>(
        w1, gw1, o_w1, D * H, Wm1, bm1, Wm2, bm2, M);
    k_update<<<dim3((H + NTHREADS - 1) / NTHREADS), blk, 0, stream>>>(
        b1, gb1, o_b1, H, Wm1, bm1, Wm2, bm2, M);
    k_update<<<dim3((H * D + NTHREADS - 1) / NTHREADS), blk, 0, stream>>>(
        w2, gw2, o_w2, H * D, Wm1, bm1, Wm2, bm2, M);
    k_update<<<dim3((D + NTHREADS - 1) / NTHREADS), blk, 0, stream>>>(
        b2, gb2, o_b2, D, Wm1, bm1, Wm2, bm2, M);
}

// Round 2
// 604.923 us; speedup vs baseline: 3.1418x; 3.1418x over previous
//
#include <hip/hip_runtime.h>
#include <hip/hip_bf16.h>

#define LR 0.01f
#define WD 0.01f
#define NTHREADS 256

typedef short s16x8 __attribute__((ext_vector_type(8)));
typedef float f32x4 __attribute__((ext_vector_type(4)));

__device__ __forceinline__ unsigned short f2bf(float f) {
    __hip_bfloat16 h = __float2bfloat16(f);
    return *reinterpret_cast<unsigned short*>(&h);
}
__device__ __forceinline__ float bf2f(unsigned short u) {
    __hip_bfloat16 h;
    *reinterpret_cast<unsigned short*>(&h) = u;
    return __bfloat162float(h);
}

// ---------------------------------------------------------------------------
// Stage one 128x32 bf16 tile (row-major, linear LDS [128][32]) via
// global_load_lds width=16. LDS dest = wave-uniform base + lane*16 (linear),
// so slot s = tid + q*256 maps to row=s>>2, chunk=s&3.
// ---------------------------------------------------------------------------
__device__ __forceinline__ void stage_tile(const unsigned short* g, int ldg,
                                           unsigned short* lds) {
    const int t = threadIdx.x;
#pragma unroll
    for (int q = 0; q < 2; ++q) {
        int s = t + q * 256;
        int row = s >> 2, ch = s & 3;
        const unsigned short* gp = g + (size_t)row * ldg + ch * 8;
        unsigned short* lp = lds + s * 8;
        __builtin_amdgcn_global_load_lds(
            (__attribute__((address_space(1))) void*)gp,
            (__attribute__((address_space(3))) void*)lp, 16, 0, 0);
    }
}

// ---------------------------------------------------------------------------
// MFMA GEMM: C[M,N] = A[M,K] @ Bt[N,K]^T, bf16 inputs, fp32 accum.
// 128x128 tile, BK=32, 4 waves (each 64x64 = 4x4 frags of 16x16x32).
// NPROD==3: bf16x3 (Ah*Bh + Ah*Bl + Al*Bh) for fp32-class accuracy.
// EPI: 0 = tanh+split(T_hi,T_lo)  1 = h_t + G  2 = dtanh -> dA  3 = atomicAdd
// ---------------------------------------------------------------------------
template <int NPROD, int EPI>
__global__ __launch_bounds__(NTHREADS) void k_mfma(
    const unsigned short* __restrict__ Ah, const unsigned short* __restrict__ Al,
    const unsigned short* __restrict__ Bh, const unsigned short* __restrict__ Bl,
    int Nd, int Kd, int Kslice, const float* __restrict__ bias,
    const float* __restrict__ xtgt, const unsigned short* __restrict__ Th,
    const unsigned short* __restrict__ Tl, float* __restrict__ outf,
    unsigned short* __restrict__ outb0, unsigned short* __restrict__ outb1,
    float scale) {
    constexpr int NT = (NPROD == 3) ? 4 : 2;
    __shared__ unsigned short smem[NT * 4096];
    unsigned short* sAh = smem;
    unsigned short* sBh = smem + 4096;
    unsigned short* sAl = (NPROD == 3) ? smem + 8192 : smem;
    unsigned short* sBl = (NPROD == 3) ? smem + 12288 : smem;

    const int m0 = blockIdx.y * 128, n0 = blockIdx.x * 128;
    const int kb = blockIdx.z * Kslice;

    const int lane = threadIdx.x & 63, wid = threadIdx.x >> 6;
    const int wrow = (wid >> 1) * 64, wcol = (wid & 1) * 64;
    const int lm = lane & 15;
    const int fro = (lane >> 4) * 8;  // k-chunk offset (elems)

    f32x4 acc[4][4] = {};

    const unsigned short* gA = Ah + (size_t)m0 * Kd + kb;
    const unsigned short* gB = Bh + (size_t)n0 * Kd + kb;
    const unsigned short* gAl = (NPROD == 3) ? Al + (size_t)m0 * Kd + kb : nullptr;
    const unsigned short* gBl = (NPROD == 3) ? Bl + (size_t)n0 * Kd + kb : nullptr;

    for (int k0 = 0; k0 < Kslice; k0 += 32) {
        stage_tile(gA, Kd, sAh);
        stage_tile(gB, Kd, sBh);
        if (NPROD == 3) {
            stage_tile(gAl, Kd, sAl);
            stage_tile(gBl, Kd, sBl);
        }
        gA += 32; gB += 32;
        if (NPROD == 3) { gAl += 32; gBl += 32; }
        __syncthreads();  // drains vmcnt(0): tiles ready
        s16x8 ah[4], bh[4], al[4], bl[4];
#pragma unroll
        for (int i = 0; i < 4; ++i) {
            ah[i] = *(const s16x8*)(sAh + (wrow + i * 16 + lm) * 32 + fro);
            bh[i] = *(const s16x8*)(sBh + (wcol + i * 16 + lm) * 32 + fro);
            if (NPROD == 3) {
                al[i] = *(const s16x8*)(sAl + (wrow + i * 16 + lm) * 32 + fro);
                bl[i] = *(const s16x8*)(sBl + (wcol + i * 16 + lm) * 32 + fro);
            }
        }
#pragma unroll
        for (int i = 0; i < 4; ++i)
#pragma unroll
            for (int j = 0; j < 4; ++j) {
                acc[i][j] = __builtin_amdgcn_mfma_f32_16x16x32_bf16(
                    ah[i], bh[j], acc[i][j], 0, 0, 0);
                if (NPROD == 3) {
                    acc[i][j] = __builtin_amdgcn_mfma_f32_16x16x32_bf16(
                        ah[i], bl[j], acc[i][j], 0, 0, 0);
                    acc[i][j] = __builtin_amdgcn_mfma_f32_16x16x32_bf16(
                        al[i], bh[j], acc[i][j], 0, 0, 0);
                }
            }
        __syncthreads();  // all waves done reading before next overwrite
    }

    // C/D layout (m89 verified): col = lane&15, row = (lane>>4)*4 + reg
    const int rbase = (lane >> 4) * 4;
#pragma unroll
    for (int i = 0; i < 4; ++i)
#pragma unroll
        for (int j = 0; j < 4; ++j)
#pragma unroll
            for (int r = 0; r < 4; ++r) {
                int row = m0 + wrow + i * 16 + rbase + r;
                int col = n0 + wcol + j * 16 + lm;
                size_t idx = (size_t)row * Nd + col;
                float v = acc[i][j][r];
                if (EPI == 0) {
                    float tv = tanhf(v + bias[col]);
                    unsigned short hi = f2bf(tv);
                    outb0[idx] = hi;
                    outb1[idx] = f2bf(tv - bf2f(hi));
                } else if (EPI == 1) {
                    float p = v + bias[col];
                    outf[idx] = p;
                    outb0[idx] = f2bf(scale * (p - xtgt[idx]));
                } else if (EPI == 2) {
                    float tv = bf2f(Th[idx]) + bf2f(Tl[idx]);
                    outb0[idx] = f2bf(v * (1.0f - tv * tv));
                } else {
                    atomicAdd(&outf[idx], v);
                }
            }
}

// fp32 -> bf16 hi + lo (elementwise, float4-vectorized)
__global__ void k_split(const float* __restrict__ in, unsigned short* __restrict__ hi,
                        unsigned short* __restrict__ lo, int n4) {
    int i = blockIdx.x * blockDim.x + threadIdx.x;
    if (i >= n4) return;
    float4 v = ((const float4*)in)[i];
    ushort4 h, l;
    h.x = f2bf(v.x); l.x = f2bf(v.x - bf2f(h.x));
    h.y = f2bf(v.y); l.y = f2bf(v.y - bf2f(h.y));
    h.z = f2bf(v.z); l.z = f2bf(v.z - bf2f(h.z));
    h.w = f2bf(v.w); l.w = f2bf(v.w - bf2f(h.w));
    ((ushort4*)hi)[i] = h;
    ((ushort4*)lo)[i] = l;
}

// fp32 [R,C] -> transposed bf16 hi/lo [C,R]
__global__ void k_splitT(const float* __restrict__ in, unsigned short* __restrict__ hiT,
                         unsigned short* __restrict__ loT, int R, int C) {
    __shared__ float tile[32][33];
    int tx = threadIdx.x & 31, ty = threadIdx.x >> 5;  // 32 x 8
    int c0 = blockIdx.x * 32, r0 = blockIdx.y * 32;
#pragma unroll
    for (int i = 0; i < 32; i += 8)
        tile[ty + i][tx] = in[(size_t)(r0 + ty + i) * C + c0 + tx];
    __syncthreads();
#pragma unroll
    for (int i = 0; i < 32; i += 8) {
        float v = tile[tx][ty + i];
        unsigned short h = f2bf(v);
        size_t o = (size_t)(c0 + ty + i) * R + r0 + tx;
        hiT[o] = h;
        loT[o] = f2bf(v - bf2f(h));
    }
}

// bf16 [R,C] -> [C,R]
__global__ void k_trb(const unsigned short* __restrict__ in,
                      unsigned short* __restrict__ out, int R, int C) {
    __shared__ unsigned short tile[64][65];
    int tx = threadIdx.x & 63, ty = threadIdx.x >> 6;  // 64 x 4
    int c0 = blockIdx.x * 64, r0 = blockIdx.y * 64;
#pragma unroll
    for (int i = 0; i < 64; i += 4)
        tile[ty + i][tx] = in[(size_t)(r0 + ty + i) * C + c0 + tx];
    __syncthreads();
#pragma unroll
    for (int i = 0; i < 64; i += 4)
        out[(size_t)(c0 + ty + i) * R + r0 + tx] = tile[tx][ty + i];
}

// column sum of bf16 matrix chunk -> atomicAdd fp32
__global__ void k_colsum_bf16(const unsigned short* __restrict__ src,
                              float* __restrict__ dst, int C, int rowsPer) {
    int col = blockIdx.x * blockDim.x + threadIdx.x;
    int r0 = blockIdx.y * rowsPer;
    float s = 0.f;
    for (int r = r0; r < r0 + rowsPer; ++r) s += bf2f(src[(size_t)r * C + col]);
    atomicAdd(&dst[col], s);
}

// learned-optimizer elementwise update
__global__ void k_update(const float* __restrict__ p, const float* __restrict__ g,
                         float* __restrict__ out, int n,
                         const float* __restrict__ Wm1, const float* __restrict__ bm1,
                         const float* __restrict__ Wm2, const float* __restrict__ bm2,
                         int M) {
    __shared__ float s1[64], s2[64], s3[64];
    if (threadIdx.x < M) {
        s1[threadIdx.x] = Wm1[threadIdx.x];
        s2[threadIdx.x] = bm1[threadIdx.x];
        s3[threadIdx.x] = Wm2[threadIdx.x];
    }
    __syncthreads();
    int i = blockIdx.x * blockDim.x + threadIdx.x;
    if (i >= n) return;
    float gv = g[i];
    float u = bm2[0];
#pragma unroll 8
    for (int m = 0; m < M; ++m) u += tanhf(fmaf(gv, s1[m], s2[m])) * s3[m];
    float pv = p[i];
    out[i] = pv - (LR * u + WD * pv);
}

__global__ void k_zero(float* __restrict__ p, int n) {
    int i = blockIdx.x * blockDim.x + threadIdx.x;
    if (i < n) p[i] = 0.f;
}

extern "C" void kernel_launch(void* const* d_in, const int* in_sizes, int n_in,
                              void* d_out, int out_size, void* d_ws, size_t ws_size,
                              hipStream_t stream) {
    const float* x_t      = (const float*)d_in[0];
    const float* x_target = (const float*)d_in[1];
    const float* w1  = (const float*)d_in[2];
    const float* b1  = (const float*)d_in[3];
    const float* w2  = (const float*)d_in[4];
    const float* b2  = (const float*)d_in[5];
    const float* Wm1 = (const float*)d_in[6];
    const float* bm1 = (const float*)d_in[7];
    const float* Wm2 = (const float*)d_in[8];
    const float* bm2 = (const float*)d_in[9];

    const int H = in_sizes[3];      // 1024
    const int D = in_sizes[5];      // 512
    const int N = in_sizes[0] / D;  // 16384
    const int M = in_sizes[6];      // 32

    // ---- workspace layout (gw2,gw1,gb1,gb2 contiguous for single k_zero) ----
    char* w = (char*)d_ws;
    float* gw2 = (float*)w;               w += (size_t)H * D * 4;
    float* gw1 = (float*)w;               w += (size_t)D * H * 4;
    float* gb1 = (float*)w;               w += (size_t)H * 4;
    float* gb2 = (float*)w;               w += (size_t)D * 4;
    unsigned short* T_hi = (unsigned short*)w;  w += (size_t)N * H * 2;
    unsigned short* T_lo = (unsigned short*)w;  w += (size_t)N * H * 2;
    unsigned short* Gb   = (unsigned short*)w;  w += (size_t)N * D * 2;
    unsigned short* dAb  = (unsigned short*)w;  w += (size_t)N * H * 2;
    unsigned short* x_hi = (unsigned short*)w;  w += (size_t)N * D * 2;
    unsigned short* x_lo = (unsigned short*)w;  w += (size_t)N * D * 2;
    unsigned short* xT   = (unsigned short*)w;  w += (size_t)N * D * 2;
    unsigned short* TT   = (unsigned short*)w;  w += (size_t)N * H * 2;
    unsigned short* w1T_hi = (unsigned short*)w; w += (size_t)D * H * 2;
    unsigned short* w1T_lo = (unsigned short*)w; w += (size_t)D * H * 2;
    unsigned short* w2T_hi = (unsigned short*)w; w += (size_t)D * H * 2;
    unsigned short* w2T_lo = (unsigned short*)w; w += (size_t)D * H * 2;
    unsigned short* w2b_hi = (unsigned short*)w; w += (size_t)H * D * 2;
    unsigned short* w2b_lo = (unsigned short*)w; w += (size_t)H * D * 2;
    // aliases (lifetimes verified: x_lo dead after fwd1; T_lo dead after dA-epi)
    unsigned short* GT  = x_lo;  // [D,N]
    unsigned short* dAT = T_lo;  // [H,N]

    float* out  = (float*)d_out;
    float* h_t  = out;                    // [N,D]
    float* o_w1 = h_t + (size_t)N * D;    // [D,H]
    float* o_b1 = o_w1 + (size_t)D * H;   // [H]
    float* o_w2 = o_b1 + H;               // [H,D]
    float* o_b2 = o_w2 + (size_t)H * D;   // [D]

    dim3 blk(NTHREADS);
    const float scale = 2.0f / ((float)N * (float)D);

    // zero atomic accumulators
    int zn = H * D + D * H + H + D;
    k_zero<<<dim3((zn + NTHREADS - 1) / NTHREADS), blk, 0, stream>>>(gw2, zn);

    // conversions / transposes of inputs
    k_split<<<dim3(N * D / 4 / NTHREADS), blk, 0, stream>>>(x_t, x_hi, x_lo, N * D / 4);
    k_split<<<dim3(H * D / 4 / NTHREADS), blk, 0, stream>>>(w2, w2b_hi, w2b_lo, H * D / 4);
    k_splitT<<<dim3(H / 32, D / 32), blk, 0, stream>>>(w1, w1T_hi, w1T_lo, D, H);
    k_splitT<<<dim3(D / 32, H / 32), blk, 0, stream>>>(w2, w2T_hi, w2T_lo, H, D);
    k_trb<<<dim3(D / 64, N / 64), blk, 0, stream>>>(x_hi, xT, N, D);

    // fwd1: T = tanh(x@w1 + b1), bf16x3, write T_hi/T_lo
    k_mfma<3, 0><<<dim3(H / 128, N / 128, 1), blk, 0, stream>>>(
        x_hi, x_lo, w1T_hi, w1T_lo, H, D, D, b1, nullptr, nullptr, nullptr,
        nullptr, T_hi, T_lo, 0.f);

    // fwd2: h = T@w2 + b2 (fp32 out), G = scale*(h - xtgt) (bf16)
    k_mfma<3, 1><<<dim3(D / 128, N / 128, 1), blk, 0, stream>>>(
        T_hi, T_lo, w2T_hi, w2T_lo, D, H, H, b2, x_target, nullptr, nullptr,
        h_t, Gb, nullptr, scale);

    // transposes for grad GEMMs
    k_trb<<<dim3(H / 64, N / 64), blk, 0, stream>>>(T_hi, TT, N, H);
    k_trb<<<dim3(D / 64, N / 64), blk, 0, stream>>>(Gb, GT, N, D);

    // dA = (G @ w2^T) * (1 - T^2)  -> bf16
    k_mfma<1, 2><<<dim3(H / 128, N / 128, 1), blk, 0, stream>>>(
        Gb, nullptr, w2b_hi, nullptr, H, D, D, nullptr, nullptr, T_hi, T_lo,
        nullptr, dAb, nullptr, 0.f);

    k_trb<<<dim3(H / 64, N / 64), blk, 0, stream>>>(dAb, dAT, N, H);

    // gw2 = T^T @ G  [H,D], split-K=16 with fp32 atomics
    const int SPLIT = 16;
    k_mfma<1, 3><<<dim3(D / 128, H / 128, SPLIT), blk, 0, stream>>>(
        TT, nullptr, GT, nullptr, D, N, N / SPLIT, nullptr, nullptr, nullptr,
        nullptr, gw2, nullptr, nullptr, 0.f);

    // gw1 = x^T @ dA  [D,H]
    k_mfma<1, 3><<<dim3(H / 128, D / 128, SPLIT), blk, 0, stream>>>(
        xT, nullptr, dAT, nullptr, H, N, N / SPLIT, nullptr, nullptr, nullptr,
        nullptr, gw1, nullptr, nullptr, 0.f);

    // bias grads
    k_colsum_bf16<<<dim3(H / NTHREADS, 64), blk, 0, stream>>>(dAb, gb1, H, N / 64);
    k_colsum_bf16<<<dim3(D / NTHREADS, 64), blk, 0, stream>>>(Gb, gb2, D, N / 64);

    // learned-optimizer updates
    k_update<<<dim3((D * H + NTHREADS - 1) / NTHREADS), blk, 0, stream>>>(
        w1, gw1, o_w1, D * H, Wm1, bm1, Wm2, bm2, M);
    k_update<<<dim3((H + NTHREADS - 1) / NTHREADS), blk, 0, stream>>>(
        b1, gb1, o_b1, H, Wm1, bm1, Wm2, bm2, M);
    k_update<<<dim3((H * D + NTHREADS - 1) / NTHREADS), blk, 0, stream>>>(
        w2, gw2, o_w2, H * D, Wm1, bm1, Wm2, bm2, M);
    k_update<<<dim3((D + NTHREADS - 1) / NTHREADS), blk, 0, stream>>>(
        b2, gb2, o_b2, D, Wm1, bm1, Wm2, bm2, M);
}

// Round 3
// 475.090 us; speedup vs baseline: 4.0004x; 1.2733x over previous
//
#include <hip/hip_runtime.h>
#include <hip/hip_bf16.h>

#define LR 0.01f
#define WD 0.01f
#define NTHREADS 256

typedef short s16x8 __attribute__((ext_vector_type(8)));
typedef float f32x4 __attribute__((ext_vector_type(4)));
typedef unsigned short u16;

__device__ __forceinline__ u16 f2bf(float f) {
    __hip_bfloat16 h = __float2bfloat16(f);
    return *reinterpret_cast<u16*>(&h);
}
__device__ __forceinline__ float bf2f(u16 u) {
    __hip_bfloat16 h;
    *reinterpret_cast<u16*>(&h) = u;
    return __bfloat162float(h);
}

// ---------------------------------------------------------------------------
// Stage a paired tile [128 rows][A-chunks 0..3 | B-chunks 4..7] (128B rows)
// into linear LDS with XOR swizzle chl = chp ^ (row&7) applied on the GLOBAL
// source (rule #21: gload_lds writes linearly; source permutation == read
// permutation). 1024 slots of 16B, 4 issues per 256 threads.
// ---------------------------------------------------------------------------
__device__ __forceinline__ void stage_pair(const u16* gA, const u16* gB, int ldg,
                                           u16* lds) {
    const int t = threadIdx.x;
#pragma unroll
    for (int q = 0; q < 4; ++q) {
        int s = t + q * 256;
        int row = s >> 3, chp = s & 7;
        int chl = chp ^ (row & 7);
        const u16* gp = (chl < 4) ? (gA + (size_t)row * ldg + chl * 8)
                                  : (gB + (size_t)row * ldg + (chl & 3) * 8);
        __builtin_amdgcn_global_load_lds(
            (const __attribute__((address_space(1))) void*)gp,
            (__attribute__((address_space(3))) void*)(lds + s * 8), 16, 0, 0);
    }
}

// swizzled fragment read: logical chunk c (A: 0..3, B: 4..7) of row r
__device__ __forceinline__ s16x8 frag(const u16* P, int r, int c) {
    return *(const s16x8*)(P + r * 64 + ((c ^ (r & 7)) * 8));
}

// ---------------------------------------------------------------------------
// MFMA GEMM: C[M,N] = A[M,K] @ Bt[N,K]^T, bf16 in, fp32 accum.
// 128x128 tile, BK=32, 4 waves (64x64 each = 4x4 frags of 16x16x32).
// NPROD: 3 = Ah*Bh+Ah*Bl+Al*Bh ; 2 = Ah*Bh+Ah*Bl ; 1 = plain.
// EPI: 0 = tanh -> T_hi(rm) + TT(transposed)
//      1 = h_t(fp32 rm) + G(rm) + GT(transposed)
//      2 = dtanh -> dAT (transposed only)
//      3 = atomicAdd fp32 (split-K weight grads)
// ---------------------------------------------------------------------------
template <int NPROD, int EPI>
__global__ __launch_bounds__(NTHREADS) void k_mfma(
    const u16* __restrict__ Ah, const u16* __restrict__ Al,
    const u16* __restrict__ Bh, const u16* __restrict__ Bl,
    int Md, int Nd, int Kd, int Kslice,
    const float* __restrict__ bias, const float* __restrict__ xtgt,
    const u16* __restrict__ Th,
    float* __restrict__ outf, u16* __restrict__ outb, u16* __restrict__ outbT,
    float scale) {
    __shared__ u16 smem[(NPROD > 1 ? 2 : 1) * 8192];
    u16* P1 = smem;
    u16* P2 = smem + 8192;

    const int m0 = blockIdx.y * 128, n0 = blockIdx.x * 128;
    const int kb = blockIdx.z * Kslice;
    const int lane = threadIdx.x & 63, wid = threadIdx.x >> 6;
    const int wrow = (wid >> 1) * 64, wcol = (wid & 1) * 64;
    const int lm = lane & 15;
    const int cA = lane >> 4;  // k-chunk 0..3

    f32x4 acc[4][4] = {};

    const u16* gAh = Ah + (size_t)m0 * Kd + kb;
    const u16* gBh = Bh + (size_t)n0 * Kd + kb;
    const u16* gAl = (NPROD == 3) ? Al + (size_t)m0 * Kd + kb : nullptr;
    const u16* gBl = (NPROD >= 2) ? Bl + (size_t)n0 * Kd + kb : nullptr;

    for (int k0 = 0; k0 < Kslice; k0 += 32) {
        stage_pair(gAh, gBh, Kd, P1);
        if (NPROD == 3) stage_pair(gAl, gBl, Kd, P2);
        if (NPROD == 2) stage_pair(gBl, gBl, Kd, P2);  // Bl at logical chunks 0..3
        gAh += 32; gBh += 32;
        if (NPROD == 3) gAl += 32;
        if (NPROD >= 2) gBl += 32;
        __syncthreads();  // drains vmcnt(0): tiles ready
        s16x8 ah[4], bh[4], al[4], bl[4];
#pragma unroll
        for (int i = 0; i < 4; ++i) {
            ah[i] = frag(P1, wrow + i * 16 + lm, cA);
            bh[i] = frag(P1, wcol + i * 16 + lm, cA + 4);
            if (NPROD == 3) {
                al[i] = frag(P2, wrow + i * 16 + lm, cA);
                bl[i] = frag(P2, wcol + i * 16 + lm, cA + 4);
            }
            if (NPROD == 2) bl[i] = frag(P2, wcol + i * 16 + lm, cA);
        }
#pragma unroll
        for (int i = 0; i < 4; ++i)
#pragma unroll
            for (int j = 0; j < 4; ++j) {
                acc[i][j] = __builtin_amdgcn_mfma_f32_16x16x32_bf16(
                    ah[i], bh[j], acc[i][j], 0, 0, 0);
                if (NPROD >= 2)
                    acc[i][j] = __builtin_amdgcn_mfma_f32_16x16x32_bf16(
                        ah[i], bl[j], acc[i][j], 0, 0, 0);
                if (NPROD == 3)
                    acc[i][j] = __builtin_amdgcn_mfma_f32_16x16x32_bf16(
                        al[i], bh[j], acc[i][j], 0, 0, 0);
            }
        __syncthreads();  // all waves done reading before next overwrite
    }

    // C/D layout (m89): col = lane&15, row = (lane>>4)*4 + reg
    const int rbase = (lane >> 4) * 4;
#pragma unroll
    for (int i = 0; i < 4; ++i) {
        const int row0 = m0 + wrow + i * 16 + rbase;
#pragma unroll
        for (int j = 0; j < 4; ++j) {
            const int col = n0 + wcol + j * 16 + lm;
            if (EPI == 0) {
                ushort4 hv;
                float t0 = tanhf(acc[i][j][0] + bias[col]);
                float t1 = tanhf(acc[i][j][1] + bias[col]);
                float t2 = tanhf(acc[i][j][2] + bias[col]);
                float t3 = tanhf(acc[i][j][3] + bias[col]);
                hv.x = f2bf(t0); hv.y = f2bf(t1); hv.z = f2bf(t2); hv.w = f2bf(t3);
                outb[(size_t)(row0 + 0) * Nd + col] = hv.x;
                outb[(size_t)(row0 + 1) * Nd + col] = hv.y;
                outb[(size_t)(row0 + 2) * Nd + col] = hv.z;
                outb[(size_t)(row0 + 3) * Nd + col] = hv.w;
                *(ushort4*)(outbT + (size_t)col * Md + row0) = hv;
            } else if (EPI == 1) {
                ushort4 gv;
#pragma unroll
                for (int r = 0; r < 4; ++r) {
                    size_t idx = (size_t)(row0 + r) * Nd + col;
                    float p = acc[i][j][r] + bias[col];
                    outf[idx] = p;
                    u16 g = f2bf(scale * (p - xtgt[idx]));
                    outb[idx] = g;
                    ((u16*)&gv)[r] = g;
                }
                *(ushort4*)(outbT + (size_t)col * Md + row0) = gv;
            } else if (EPI == 2) {
                ushort4 dv;
#pragma unroll
                for (int r = 0; r < 4; ++r) {
                    size_t idx = (size_t)(row0 + r) * Nd + col;
                    float tv = bf2f(Th[idx]);
                    ((u16*)&dv)[r] = f2bf(acc[i][j][r] * (1.0f - tv * tv));
                }
                *(ushort4*)(outbT + (size_t)col * Md + row0) = dv;
            } else {
#pragma unroll
                for (int r = 0; r < 4; ++r)
                    atomicAdd(&outf[(size_t)(row0 + r) * Nd + col], acc[i][j][r]);
            }
        }
    }
}

// ---------------------------------------------------------------------------
// fp32 [R,C] -> optional {hi,lo} row-major bf16 + optional {hi,lo} transposed
// ---------------------------------------------------------------------------
__global__ void k_prep(const float* __restrict__ in, u16* __restrict__ hiRM,
                       u16* __restrict__ loRM, u16* __restrict__ hiT,
                       u16* __restrict__ loT, int R, int C) {
    __shared__ float tile[64][65];
    const int tx = threadIdx.x & 63, ty = threadIdx.x >> 6;
    const int c0 = blockIdx.x * 64, r0 = blockIdx.y * 64;
#pragma unroll
    for (int i = 0; i < 64; i += 4) {
        size_t idx = (size_t)(r0 + ty + i) * C + c0 + tx;
        float v = in[idx];
        tile[ty + i][tx] = v;
        if (hiRM) {
            u16 h = f2bf(v);
            hiRM[idx] = h;
            if (loRM) loRM[idx] = f2bf(v - bf2f(h));
        }
    }
    __syncthreads();
    if (hiT) {
#pragma unroll
        for (int i = 0; i < 64; i += 4) {
            float v = tile[tx][ty + i];
            u16 h = f2bf(v);
            size_t o = (size_t)(c0 + ty + i) * R + r0 + tx;
            hiT[o] = h;
            if (loT) loT[o] = f2bf(v - bf2f(h));
        }
    }
}

// row-sum of bf16 [R,C] -> fp32 dst[R]; one wave per row
__global__ void k_rowsum(const u16* __restrict__ src, float* __restrict__ dst,
                         int C) {
    const int row = blockIdx.x * 4 + (threadIdx.x >> 6);
    const int lane = threadIdx.x & 63;
    const u16* p = src + (size_t)row * C;
    float s = 0.f;
    for (int c = lane * 8; c < C; c += 64 * 8) {
        s16x8 v = *(const s16x8*)(p + c);
#pragma unroll
        for (int e = 0; e < 8; ++e) s += bf2f((u16)v[e]);
    }
#pragma unroll
    for (int off = 32; off; off >>= 1) s += __shfl_down(s, off);
    if (lane == 0) dst[row] = s;
}

// learned-optimizer elementwise update
__global__ void k_update(const float* __restrict__ p, const float* __restrict__ g,
                         float* __restrict__ out, int n,
                         const float* __restrict__ Wm1, const float* __restrict__ bm1,
                         const float* __restrict__ Wm2, const float* __restrict__ bm2,
                         int M) {
    __shared__ float s1[64], s2[64], s3[64];
    if (threadIdx.x < M) {
        s1[threadIdx.x] = Wm1[threadIdx.x];
        s2[threadIdx.x] = bm1[threadIdx.x];
        s3[threadIdx.x] = Wm2[threadIdx.x];
    }
    __syncthreads();
    int i = blockIdx.x * blockDim.x + threadIdx.x;
    if (i >= n) return;
    float gv = g[i];
    float u = bm2[0];
#pragma unroll 8
    for (int m = 0; m < M; ++m) u += tanhf(fmaf(gv, s1[m], s2[m])) * s3[m];
    float pv = p[i];
    out[i] = pv - (LR * u + WD * pv);
}

__global__ void k_zero(float* __restrict__ p, int n) {
    int i = blockIdx.x * blockDim.x + threadIdx.x;
    if (i < n) p[i] = 0.f;
}

extern "C" void kernel_launch(void* const* d_in, const int* in_sizes, int n_in,
                              void* d_out, int out_size, void* d_ws, size_t ws_size,
                              hipStream_t stream) {
    const float* x_t      = (const float*)d_in[0];
    const float* x_target = (const float*)d_in[1];
    const float* w1  = (const float*)d_in[2];
    const float* b1  = (const float*)d_in[3];
    const float* w2  = (const float*)d_in[4];
    const float* b2  = (const float*)d_in[5];
    const float* Wm1 = (const float*)d_in[6];
    const float* bm1 = (const float*)d_in[7];
    const float* Wm2 = (const float*)d_in[8];
    const float* bm2 = (const float*)d_in[9];

    const int H = in_sizes[3];      // 1024
    const int D = in_sizes[5];      // 512
    const int N = in_sizes[0] / D;  // 16384
    const int M = in_sizes[6];      // 32

    // ---- workspace (gw2,gw1 contiguous for single k_zero) ----
    char* w = (char*)d_ws;
    float* gw2 = (float*)w;            w += (size_t)H * D * 4;
    float* gw1 = (float*)w;            w += (size_t)D * H * 4;
    float* gb1 = (float*)w;            w += (size_t)H * 4;
    float* gb2 = (float*)w;            w += (size_t)D * 4;
    u16* T_hi = (u16*)w;               w += (size_t)N * H * 2;
    u16* TT   = (u16*)w;               w += (size_t)N * H * 2;
    u16* dAT  = (u16*)w;               w += (size_t)N * H * 2;
    u16* Gb   = (u16*)w;               w += (size_t)N * D * 2;
    u16* x_hi = (u16*)w;               w += (size_t)N * D * 2;
    u16* x_lo = (u16*)w;               w += (size_t)N * D * 2;
    u16* xT   = (u16*)w;               w += (size_t)N * D * 2;
    u16* w1T_hi = (u16*)w;             w += (size_t)D * H * 2;
    u16* w1T_lo = (u16*)w;             w += (size_t)D * H * 2;
    u16* w2T_hi = (u16*)w;             w += (size_t)D * H * 2;
    u16* w2T_lo = (u16*)w;             w += (size_t)D * H * 2;
    u16* w2b_hi = (u16*)w;             w += (size_t)H * D * 2;
    // alias: x_lo dead after fwd1; GT written in fwd2 epilogue (later kernel)
    u16* GT = x_lo;  // [D,N]

    float* out  = (float*)d_out;
    float* h_t  = out;                    // [N,D]
    float* o_w1 = h_t + (size_t)N * D;    // [D,H]
    float* o_b1 = o_w1 + (size_t)D * H;   // [H]
    float* o_w2 = o_b1 + H;               // [H,D]
    float* o_b2 = o_w2 + (size_t)H * D;   // [D]

    dim3 blk(NTHREADS);
    const float scale = 2.0f / ((float)N * (float)D);

    // zero atomic accumulators (gw2, gw1 contiguous)
    int zn = H * D + D * H;
    k_zero<<<dim3((zn + NTHREADS - 1) / NTHREADS), blk, 0, stream>>>(gw2, zn);

    // input prep: x -> x_hi, x_lo (rm) + xT (transposed hi) ; w1 -> w1T hi/lo ;
    // w2 -> w2b_hi (rm) + w2T hi/lo
    k_prep<<<dim3(D / 64, N / 64), blk, 0, stream>>>(x_t, x_hi, x_lo, xT, nullptr, N, D);
    k_prep<<<dim3(H / 64, D / 64), blk, 0, stream>>>(w1, nullptr, nullptr, w1T_hi, w1T_lo, D, H);
    k_prep<<<dim3(D / 64, H / 64), blk, 0, stream>>>(w2, w2b_hi, nullptr, w2T_hi, w2T_lo, H, D);

    // fwd1: T = tanh(x@w1 + b1)  bf16x3 -> T_hi (rm) + TT (transposed)
    k_mfma<3, 0><<<dim3(H / 128, N / 128, 1), blk, 0, stream>>>(
        x_hi, x_lo, w1T_hi, w1T_lo, N, H, D, D, b1, nullptr, nullptr,
        nullptr, T_hi, TT, 0.f);

    // fwd2: h = T@w2 + b2 (fp32) ; G = scale*(h - xtgt) -> Gb (rm) + GT (T)
    k_mfma<2, 1><<<dim3(D / 128, N / 128, 1), blk, 0, stream>>>(
        T_hi, nullptr, w2T_hi, w2T_lo, N, D, H, H, b2, x_target, nullptr,
        h_t, Gb, GT, scale);

    // dA = (G @ w2^T) * (1 - T^2) -> dAT (transposed only)
    k_mfma<1, 2><<<dim3(H / 128, N / 128, 1), blk, 0, stream>>>(
        Gb, nullptr, w2b_hi, nullptr, N, H, D, D, nullptr, nullptr, T_hi,
        nullptr, nullptr, dAT, 0.f);

    // gw2 = T^T @ G  [H,D]: A=TT[H,N], Bt=GT[D,N], split-K=16, atomics
    const int SPLIT = 16;
    k_mfma<1, 3><<<dim3(D / 128, H / 128, SPLIT), blk, 0, stream>>>(
        TT, nullptr, GT, nullptr, H, D, N, N / SPLIT, nullptr, nullptr, nullptr,
        gw2, nullptr, nullptr, 0.f);

    // gw1 = x^T @ dA  [D,H]: A=xT[D,N], Bt=dAT[H,N]
    k_mfma<1, 3><<<dim3(H / 128, D / 128, SPLIT), blk, 0, stream>>>(
        xT, nullptr, dAT, nullptr, D, H, N, N / SPLIT, nullptr, nullptr, nullptr,
        gw1, nullptr, nullptr, 0.f);

    // bias grads: row-sums of transposed buffers (coalesced, no atomics)
    k_rowsum<<<dim3(H / 4), blk, 0, stream>>>(dAT, gb1, N);
    k_rowsum<<<dim3(D / 4), blk, 0, stream>>>(GT, gb2, N);

    // learned-optimizer updates
    k_update<<<dim3((D * H + NTHREADS - 1) / NTHREADS), blk, 0, stream>>>(
        w1, gw1, o_w1, D * H, Wm1, bm1, Wm2, bm2, M);
    k_update<<<dim3((H + NTHREADS - 1) / NTHREADS), blk, 0, stream>>>(
        b1, gb1, o_b1, H, Wm1, bm1, Wm2, bm2, M);
    k_update<<<dim3((H * D + NTHREADS - 1) / NTHREADS), blk, 0, stream>>>(
        w2, gw2, o_w2, H * D, Wm1, bm1, Wm2, bm2, M);
    k_update<<<dim3((D + NTHREADS - 1) / NTHREADS), blk, 0, stream>>>(
        b2, gb2, o_b2, D, Wm1, bm1, Wm2, bm2, M);
}

// Round 4
// 440.189 us; speedup vs baseline: 4.3176x; 1.0793x over previous
//
#include <hip/hip_runtime.h>
#include <hip/hip_bf16.h>

#define LR 0.01f
#define WD 0.01f
#define NTHREADS 256

typedef short s16x8 __attribute__((ext_vector_type(8)));
typedef float f32x4 __attribute__((ext_vector_type(4)));
typedef unsigned short u16;

__device__ __forceinline__ u16 f2bf(float f) {
    __hip_bfloat16 h = __float2bfloat16(f);
    return *reinterpret_cast<u16*>(&h);
}
__device__ __forceinline__ float bf2f(u16 u) {
    __hip_bfloat16 h;
    *reinterpret_cast<u16*>(&h) = u;
    return __bfloat162float(h);
}
// fast tanh: 1 - 2/(exp(2x)+1), clamped; ~1e-6 error (outputs bf16-quantized)
__device__ __forceinline__ float tanh_fast(float x) {
    float t = fminf(fmaxf(2.f * x, -30.f), 30.f);
    float e = __expf(t);
    return 1.f - 2.f * __builtin_amdgcn_rcpf(e + 1.f);
}

// ---------------------------------------------------------------------------
// Stage a paired tile [128 rows][A-chunks 0..3 | B-chunks 4..7] (128B rows)
// into linear LDS with XOR swizzle chl = chp ^ (row&7) applied on the GLOBAL
// source (rule #21). 1024 slots of 16B, 4 issues per 256 threads.
// ---------------------------------------------------------------------------
__device__ __forceinline__ void stage_pair(const u16* gA, const u16* gB, int ldg,
                                           u16* lds) {
    const int t = threadIdx.x;
#pragma unroll
    for (int q = 0; q < 4; ++q) {
        int s = t + q * 256;
        int row = s >> 3, chp = s & 7;
        int chl = chp ^ (row & 7);
        const u16* gp = (chl < 4) ? (gA + (size_t)row * ldg + chl * 8)
                                  : (gB + (size_t)row * ldg + (chl & 3) * 8);
        __builtin_amdgcn_global_load_lds(
            (const __attribute__((address_space(1))) void*)gp,
            (__attribute__((address_space(3))) void*)(lds + s * 8), 16, 0, 0);
    }
}

// swizzled fragment read: logical chunk c (A: 0..3, B: 4..7) of row r
__device__ __forceinline__ s16x8 frag(const u16* P, int r, int c) {
    return *(const s16x8*)(P + r * 64 + ((c ^ (r & 7)) * 8));
}

// ---------------------------------------------------------------------------
// MFMA GEMM: C[M,N] = A[M,K] @ Bt[N,K]^T, bf16 in, fp32 accum.
// 128x128 tile, BK=32, 4 waves. 2-phase double-buffered staging (T3-min):
// issue next-tile global_load_lds BEFORE current ds_read+MFMA; single
// __syncthreads per K-step drains them after compute covered the latency.
// XCD-aware block swizzle (T1) so A-panel-sharing blocks co-reside per XCD L2.
// NPROD: 3 = Ah*Bh+Ah*Bl+Al*Bh ; 2 = Ah*Bh+Ah*Bl ; 1 = plain.
// EPI: 0 tanh->T_hi+TT ; 1 h_t+G+GT ; 2 dtanh->dAT ; 3 atomicAdd (split-K)
// ---------------------------------------------------------------------------
template <int NPROD, int EPI>
__global__ __launch_bounds__(NTHREADS) void k_mfma(
    const u16* __restrict__ Ah, const u16* __restrict__ Al,
    const u16* __restrict__ Bh, const u16* __restrict__ Bl,
    int nbx, int Md, int Nd, int Kd, int Kslice,
    const float* __restrict__ bias, const float* __restrict__ xtgt,
    const u16* __restrict__ Th,
    float* __restrict__ outf, u16* __restrict__ outb, u16* __restrict__ outbT,
    float scale) {
    constexpr int PAIRS = (NPROD > 1) ? 2 : 1;
    __shared__ u16 smem[2 * PAIRS * 8192];

    // XCD swizzle: all grids have nwg % 8 == 0 (bijective simple form)
    const int nwg = gridDim.x;
    const int sw = (blockIdx.x & 7) * (nwg >> 3) + (blockIdx.x >> 3);
    const int m0 = (sw / nbx) * 128, n0 = (sw % nbx) * 128;
    const int kb = blockIdx.y * Kslice;

    const int lane = threadIdx.x & 63, wid = threadIdx.x >> 6;
    const int wrow = (wid >> 1) * 64, wcol = (wid & 1) * 64;
    const int lm = lane & 15;
    const int cA = lane >> 4;

    f32x4 acc[4][4] = {};

    const u16* gAh = Ah + (size_t)m0 * Kd + kb;
    const u16* gBh = Bh + (size_t)n0 * Kd + kb;
    const u16* gAl = (NPROD == 3) ? Al + (size_t)m0 * Kd + kb : nullptr;
    const u16* gBl = (NPROD >= 2) ? Bl + (size_t)n0 * Kd + kb : nullptr;

    auto stage_all = [&](int buf, int ko) {
        u16* base = smem + buf * (PAIRS * 8192);
        stage_pair(gAh + ko, gBh + ko, Kd, base);
        if (NPROD == 3) stage_pair(gAl + ko, gBl + ko, Kd, base + 8192);
        if (NPROD == 2) stage_pair(gBl + ko, gBl + ko, Kd, base + 8192);
    };

    stage_all(0, 0);
    __syncthreads();  // prologue drain: buf0 ready

    int cur = 0;
    for (int k0 = 0; k0 < Kslice; k0 += 32, cur ^= 1) {
        if (k0 + 32 < Kslice) stage_all(cur ^ 1, k0 + 32);  // prefetch next
        const u16* P1 = smem + cur * (PAIRS * 8192);
        const u16* P2 = P1 + 8192;
        s16x8 ah[4], bh[4], al[4], bl[4];
#pragma unroll
        for (int i = 0; i < 4; ++i) {
            ah[i] = frag(P1, wrow + i * 16 + lm, cA);
            bh[i] = frag(P1, wcol + i * 16 + lm, cA + 4);
            if (NPROD == 3) {
                al[i] = frag(P2, wrow + i * 16 + lm, cA);
                bl[i] = frag(P2, wcol + i * 16 + lm, cA + 4);
            }
            if (NPROD == 2) bl[i] = frag(P2, wcol + i * 16 + lm, cA);
        }
#pragma unroll
        for (int i = 0; i < 4; ++i)
#pragma unroll
            for (int j = 0; j < 4; ++j) {
                acc[i][j] = __builtin_amdgcn_mfma_f32_16x16x32_bf16(
                    ah[i], bh[j], acc[i][j], 0, 0, 0);
                if (NPROD >= 2)
                    acc[i][j] = __builtin_amdgcn_mfma_f32_16x16x32_bf16(
                        ah[i], bl[j], acc[i][j], 0, 0, 0);
                if (NPROD == 3)
                    acc[i][j] = __builtin_amdgcn_mfma_f32_16x16x32_bf16(
                        al[i], bh[j], acc[i][j], 0, 0, 0);
            }
        // single barrier per K-step: drains next-tile loads (latency covered
        // by the ds_read+MFMA above) + guards buffer swap
        __syncthreads();
    }

    // C/D layout (m89): col = lane&15, row = (lane>>4)*4 + reg
    const int rbase = (lane >> 4) * 4;
#pragma unroll
    for (int i = 0; i < 4; ++i) {
        const int row0 = m0 + wrow + i * 16 + rbase;
#pragma unroll
        for (int j = 0; j < 4; ++j) {
            const int col = n0 + wcol + j * 16 + lm;
            if (EPI == 0) {
                ushort4 hv;
                float b = bias[col];
                hv.x = f2bf(tanh_fast(acc[i][j][0] + b));
                hv.y = f2bf(tanh_fast(acc[i][j][1] + b));
                hv.z = f2bf(tanh_fast(acc[i][j][2] + b));
                hv.w = f2bf(tanh_fast(acc[i][j][3] + b));
                outb[(size_t)(row0 + 0) * Nd + col] = hv.x;
                outb[(size_t)(row0 + 1) * Nd + col] = hv.y;
                outb[(size_t)(row0 + 2) * Nd + col] = hv.z;
                outb[(size_t)(row0 + 3) * Nd + col] = hv.w;
                *(ushort4*)(outbT + (size_t)col * Md + row0) = hv;
            } else if (EPI == 1) {
                ushort4 gv;
#pragma unroll
                for (int r = 0; r < 4; ++r) {
                    size_t idx = (size_t)(row0 + r) * Nd + col;
                    float p = acc[i][j][r] + bias[col];
                    outf[idx] = p;
                    u16 g = f2bf(scale * (p - xtgt[idx]));
                    outb[idx] = g;
                    ((u16*)&gv)[r] = g;
                }
                *(ushort4*)(outbT + (size_t)col * Md + row0) = gv;
            } else if (EPI == 2) {
                ushort4 dv;
#pragma unroll
                for (int r = 0; r < 4; ++r) {
                    size_t idx = (size_t)(row0 + r) * Nd + col;
                    float tv = bf2f(Th[idx]);
                    ((u16*)&dv)[r] = f2bf(acc[i][j][r] * (1.0f - tv * tv));
                }
                *(ushort4*)(outbT + (size_t)col * Md + row0) = dv;
            } else {
#pragma unroll
                for (int r = 0; r < 4; ++r)
                    atomicAdd(&outf[(size_t)(row0 + r) * Nd + col], acc[i][j][r]);
            }
        }
    }
}

// ---------------------------------------------------------------------------
// fp32 [R,C] -> optional {hi,lo} row-major bf16 + optional {hi,lo} transposed
// ---------------------------------------------------------------------------
__global__ void k_prep(const float* __restrict__ in, u16* __restrict__ hiRM,
                       u16* __restrict__ loRM, u16* __restrict__ hiT,
                       u16* __restrict__ loT, int R, int C) {
    __shared__ float tile[64][65];
    const int tx = threadIdx.x & 63, ty = threadIdx.x >> 6;
    const int c0 = blockIdx.x * 64, r0 = blockIdx.y * 64;
#pragma unroll
    for (int i = 0; i < 64; i += 4) {
        size_t idx = (size_t)(r0 + ty + i) * C + c0 + tx;
        float v = in[idx];
        tile[ty + i][tx] = v;
        if (hiRM) {
            u16 h = f2bf(v);
            hiRM[idx] = h;
            if (loRM) loRM[idx] = f2bf(v - bf2f(h));
        }
    }
    __syncthreads();
    if (hiT) {
#pragma unroll
        for (int i = 0; i < 64; i += 4) {
            float v = tile[tx][ty + i];
            u16 h = f2bf(v);
            size_t o = (size_t)(c0 + ty + i) * R + r0 + tx;
            hiT[o] = h;
            if (loT) loT[o] = f2bf(v - bf2f(h));
        }
    }
}

// row-sum of bf16 [R,C] -> fp32 dst[R]; one wave per row
__global__ void k_rowsum(const u16* __restrict__ src, float* __restrict__ dst,
                         int C) {
    const int row = blockIdx.x * 4 + (threadIdx.x >> 6);
    const int lane = threadIdx.x & 63;
    const u16* p = src + (size_t)row * C;
    float s = 0.f;
    for (int c = lane * 8; c < C; c += 64 * 8) {
        s16x8 v = *(const s16x8*)(p + c);
#pragma unroll
        for (int e = 0; e < 8; ++e) s += bf2f((u16)v[e]);
    }
#pragma unroll
    for (int off = 32; off; off >>= 1) s += __shfl_down(s, off);
    if (lane == 0) dst[row] = s;
}

// learned-optimizer elementwise update
__global__ void k_update(const float* __restrict__ p, const float* __restrict__ g,
                         float* __restrict__ out, int n,
                         const float* __restrict__ Wm1, const float* __restrict__ bm1,
                         const float* __restrict__ Wm2, const float* __restrict__ bm2,
                         int M) {
    __shared__ float s1[64], s2[64], s3[64];
    if (threadIdx.x < M) {
        s1[threadIdx.x] = Wm1[threadIdx.x];
        s2[threadIdx.x] = bm1[threadIdx.x];
        s3[threadIdx.x] = Wm2[threadIdx.x];
    }
    __syncthreads();
    int i = blockIdx.x * blockDim.x + threadIdx.x;
    if (i >= n) return;
    float gv = g[i];
    float u = bm2[0];
#pragma unroll 8
    for (int m = 0; m < M; ++m) u += tanh_fast(fmaf(gv, s1[m], s2[m])) * s3[m];
    float pv = p[i];
    out[i] = pv - (LR * u + WD * pv);
}

__global__ void k_zero(float* __restrict__ p, int n) {
    int i = blockIdx.x * blockDim.x + threadIdx.x;
    if (i < n) p[i] = 0.f;
}

extern "C" void kernel_launch(void* const* d_in, const int* in_sizes, int n_in,
                              void* d_out, int out_size, void* d_ws, size_t ws_size,
                              hipStream_t stream) {
    const float* x_t      = (const float*)d_in[0];
    const float* x_target = (const float*)d_in[1];
    const float* w1  = (const float*)d_in[2];
    const float* b1  = (const float*)d_in[3];
    const float* w2  = (const float*)d_in[4];
    const float* b2  = (const float*)d_in[5];
    const float* Wm1 = (const float*)d_in[6];
    const float* bm1 = (const float*)d_in[7];
    const float* Wm2 = (const float*)d_in[8];
    const float* bm2 = (const float*)d_in[9];

    const int H = in_sizes[3];      // 1024
    const int D = in_sizes[5];      // 512
    const int N = in_sizes[0] / D;  // 16384
    const int M = in_sizes[6];      // 32

    // ---- workspace (gw2,gw1 contiguous for single k_zero) ----
    char* w = (char*)d_ws;
    float* gw2 = (float*)w;            w += (size_t)H * D * 4;
    float* gw1 = (float*)w;            w += (size_t)D * H * 4;
    float* gb1 = (float*)w;            w += (size_t)H * 4;
    float* gb2 = (float*)w;            w += (size_t)D * 4;
    u16* T_hi = (u16*)w;               w += (size_t)N * H * 2;
    u16* TT   = (u16*)w;               w += (size_t)N * H * 2;
    u16* dAT  = (u16*)w;               w += (size_t)N * H * 2;
    u16* Gb   = (u16*)w;               w += (size_t)N * D * 2;
    u16* x_hi = (u16*)w;               w += (size_t)N * D * 2;
    u16* x_lo = (u16*)w;               w += (size_t)N * D * 2;
    u16* xT   = (u16*)w;               w += (size_t)N * D * 2;
    u16* w1T_hi = (u16*)w;             w += (size_t)D * H * 2;
    u16* w1T_lo = (u16*)w;             w += (size_t)D * H * 2;
    u16* w2T_hi = (u16*)w;             w += (size_t)D * H * 2;
    u16* w2T_lo = (u16*)w;             w += (size_t)D * H * 2;
    u16* w2b_hi = (u16*)w;             w += (size_t)H * D * 2;
    // alias: x_lo dead after fwd1; GT written in fwd2 epilogue (later kernel)
    u16* GT = x_lo;  // [D,N]

    float* out  = (float*)d_out;
    float* h_t  = out;                    // [N,D]
    float* o_w1 = h_t + (size_t)N * D;    // [D,H]
    float* o_b1 = o_w1 + (size_t)D * H;   // [H]
    float* o_w2 = o_b1 + H;               // [H,D]
    float* o_b2 = o_w2 + (size_t)H * D;   // [D]

    dim3 blk(NTHREADS);
    const float scale = 2.0f / ((float)N * (float)D);

    // zero atomic accumulators (gw2, gw1 contiguous)
    int zn = H * D + D * H;
    k_zero<<<dim3((zn + NTHREADS - 1) / NTHREADS), blk, 0, stream>>>(gw2, zn);

    // input prep
    k_prep<<<dim3(D / 64, N / 64), blk, 0, stream>>>(x_t, x_hi, x_lo, xT, nullptr, N, D);
    k_prep<<<dim3(H / 64, D / 64), blk, 0, stream>>>(w1, nullptr, nullptr, w1T_hi, w1T_lo, D, H);
    k_prep<<<dim3(D / 64, H / 64), blk, 0, stream>>>(w2, w2b_hi, nullptr, w2T_hi, w2T_lo, H, D);

    // fwd1: T = tanh(x@w1 + b1)  bf16x3 -> T_hi (rm) + TT (transposed)
    k_mfma<3, 0><<<dim3((H / 128) * (N / 128), 1), blk, 0, stream>>>(
        x_hi, x_lo, w1T_hi, w1T_lo, H / 128, N, H, D, D, b1, nullptr, nullptr,
        nullptr, T_hi, TT, 0.f);

    // fwd2: h = T@w2 + b2 (fp32) ; G = scale*(h - xtgt) -> Gb (rm) + GT (T)
    k_mfma<2, 1><<<dim3((D / 128) * (N / 128), 1), blk, 0, stream>>>(
        T_hi, nullptr, w2T_hi, w2T_lo, D / 128, N, D, H, H, b2, x_target, nullptr,
        h_t, Gb, GT, scale);

    // dA = (G @ w2^T) * (1 - T^2) -> dAT (transposed only)
    k_mfma<1, 2><<<dim3((H / 128) * (N / 128), 1), blk, 0, stream>>>(
        Gb, nullptr, w2b_hi, nullptr, H / 128, N, H, D, D, nullptr, nullptr, T_hi,
        nullptr, nullptr, dAT, 0.f);

    // gw2 = T^T @ G  [H,D]: A=TT[H,N], Bt=GT[D,N], split-K=16, atomics
    const int SPLIT = 16;
    k_mfma<1, 3><<<dim3((D / 128) * (H / 128), SPLIT), blk, 0, stream>>>(
        TT, nullptr, GT, nullptr, D / 128, H, D, N, N / SPLIT, nullptr, nullptr,
        nullptr, gw2, nullptr, nullptr, 0.f);

    // gw1 = x^T @ dA  [D,H]: A=xT[D,N], Bt=dAT[H,N]
    k_mfma<1, 3><<<dim3((H / 128) * (D / 128), SPLIT), blk, 0, stream>>>(
        xT, nullptr, dAT, nullptr, H / 128, D, H, N, N / SPLIT, nullptr, nullptr,
        nullptr, gw1, nullptr, nullptr, 0.f);

    // bias grads: row-sums of transposed buffers (coalesced, no atomics)
    k_rowsum<<<dim3(H / 4), blk, 0, stream>>>(dAT, gb1, N);
    k_rowsum<<<dim3(D / 4), blk, 0, stream>>>(GT, gb2, N);

    // learned-optimizer updates
    k_update<<<dim3((D * H + NTHREADS - 1) / NTHREADS), blk, 0, stream>>>(
        w1, gw1, o_w1, D * H, Wm1, bm1, Wm2, bm2, M);
    k_update<<<dim3((H + NTHREADS - 1) / NTHREADS), blk, 0, stream>>>(
        b1, gb1, o_b1, H, Wm1, bm1, Wm2, bm2, M);
    k_update<<<dim3((H * D + NTHREADS - 1) / NTHREADS), blk, 0, stream>>>(
        w2, gw2, o_w2, H * D, Wm1, bm1, Wm2, bm2, M);
    k_update<<<dim3((D + NTHREADS - 1) / NTHREADS), blk, 0, stream>>>(
        b2, gb2, o_b2, D, Wm1, bm1, Wm2, bm2, M);
}

// Round 5
// 421.995 us; speedup vs baseline: 4.5037x; 1.0431x over previous
//
#include <hip/hip_runtime.h>
#include <hip/hip_bf16.h>

#define LR 0.01f
#define WD 0.01f
#define NTHREADS 256
#define SCALE_G 1048576.0f      // 2^20: lift G out of f16-subnormal range
#define INV_SCALE_G 9.5367431640625e-07f  // 2^-20

typedef short s16x8 __attribute__((ext_vector_type(8)));
typedef _Float16 f16x8 __attribute__((ext_vector_type(8)));
typedef float f32x4 __attribute__((ext_vector_type(4)));
typedef unsigned short u16;

__device__ __forceinline__ u16 f2h(float f) {
    _Float16 h = (_Float16)f;
    return *reinterpret_cast<u16*>(&h);
}
__device__ __forceinline__ float h2f(u16 u) {
    _Float16 h;
    *reinterpret_cast<u16*>(&h) = u;
    return (float)h;
}
// fast tanh: 1 - 2/(exp(2x)+1), clamped; ~1e-6 error
__device__ __forceinline__ float tanh_fast(float x) {
    float t = fminf(fmaxf(2.f * x, -30.f), 30.f);
    float e = __expf(t);
    return 1.f - 2.f * __builtin_amdgcn_rcpf(e + 1.f);
}

// ---------------------------------------------------------------------------
// Stage a paired tile [128 rows][A-chunks 0..3 | B-chunks 4..7] (128B rows)
// into linear LDS with XOR swizzle chl = chp ^ (row&7) applied on the GLOBAL
// source (rule #21). 1024 slots of 16B, 4 issues per 256 threads.
// ---------------------------------------------------------------------------
__device__ __forceinline__ void stage_pair(const u16* gA, const u16* gB, int ldg,
                                           u16* lds) {
    const int t = threadIdx.x;
#pragma unroll
    for (int q = 0; q < 4; ++q) {
        int s = t + q * 256;
        int row = s >> 3, chp = s & 7;
        int chl = chp ^ (row & 7);
        const u16* gp = (chl < 4) ? (gA + (size_t)row * ldg + chl * 8)
                                  : (gB + (size_t)row * ldg + (chl & 3) * 8);
        __builtin_amdgcn_global_load_lds(
            (const __attribute__((address_space(1))) void*)gp,
            (__attribute__((address_space(3))) void*)(lds + s * 8), 16, 0, 0);
    }
}

// swizzled fragment read: logical chunk c (A: 0..3, B: 4..7) of row r
__device__ __forceinline__ f16x8 frag(const u16* P, int r, int c) {
    return *(const f16x8*)(P + r * 64 + ((c ^ (r & 7)) * 8));
}

// ---------------------------------------------------------------------------
// MFMA GEMM: C[M,N] = A[M,K] @ Bt[N,K]^T, f16 in, fp32 accum.
// 128x128 tile, BK=32, 4 waves, 2-phase double-buffered staging, XCD swizzle.
// EPI: 0 tanh->T(rm)+TT ; 1 h_t(fp32)+G'(rm)+GT' (G scaled by SCALE_G) ;
//      2 dtanh->dAT ; 3 atomicAdd fp32 (split-K weight grads)
// ---------------------------------------------------------------------------
template <int EPI>
__global__ __launch_bounds__(NTHREADS) void k_mfma(
    const u16* __restrict__ A, const u16* __restrict__ Bt,
    int nbx, int Md, int Nd, int Kd, int Kslice,
    const float* __restrict__ bias, const float* __restrict__ xtgt,
    const u16* __restrict__ Th,
    float* __restrict__ outf, u16* __restrict__ outb, u16* __restrict__ outbT,
    float scale) {
    __shared__ u16 smem[2 * 8192];

    // XCD swizzle (all grids have nwg % 8 == 0)
    const int nwg = gridDim.x;
    const int sw = (blockIdx.x & 7) * (nwg >> 3) + (blockIdx.x >> 3);
    const int m0 = (sw / nbx) * 128, n0 = (sw % nbx) * 128;
    const int kb = blockIdx.y * Kslice;

    const int lane = threadIdx.x & 63, wid = threadIdx.x >> 6;
    const int wrow = (wid >> 1) * 64, wcol = (wid & 1) * 64;
    const int lm = lane & 15;
    const int cA = lane >> 4;

    f32x4 acc[4][4] = {};

    const u16* gA = A + (size_t)m0 * Kd + kb;
    const u16* gB = Bt + (size_t)n0 * Kd + kb;

    stage_pair(gA, gB, Kd, smem);
    __syncthreads();  // prologue drain: buf0 ready

    int cur = 0;
    for (int k0 = 0; k0 < Kslice; k0 += 32, cur ^= 1) {
        if (k0 + 32 < Kslice)
            stage_pair(gA + k0 + 32, gB + k0 + 32, Kd, smem + (cur ^ 1) * 8192);
        const u16* P1 = smem + cur * 8192;
        f16x8 a[4], b[4];
#pragma unroll
        for (int i = 0; i < 4; ++i) {
            a[i] = frag(P1, wrow + i * 16 + lm, cA);
            b[i] = frag(P1, wcol + i * 16 + lm, cA + 4);
        }
#pragma unroll
        for (int i = 0; i < 4; ++i)
#pragma unroll
            for (int j = 0; j < 4; ++j)
                acc[i][j] = __builtin_amdgcn_mfma_f32_16x16x32_f16(
                    a[i], b[j], acc[i][j], 0, 0, 0);
        // single barrier per K-step: drains prefetch (latency covered by
        // ds_read+MFMA above) + guards buffer swap
        __syncthreads();
    }

    // C/D layout (m89): col = lane&15, row = (lane>>4)*4 + reg
    const int rbase = (lane >> 4) * 4;
#pragma unroll
    for (int i = 0; i < 4; ++i) {
        const int row0 = m0 + wrow + i * 16 + rbase;
#pragma unroll
        for (int j = 0; j < 4; ++j) {
            const int col = n0 + wcol + j * 16 + lm;
            if (EPI == 0) {
                ushort4 hv;
                float bcol = bias[col];
                hv.x = f2h(tanh_fast(acc[i][j][0] + bcol));
                hv.y = f2h(tanh_fast(acc[i][j][1] + bcol));
                hv.z = f2h(tanh_fast(acc[i][j][2] + bcol));
                hv.w = f2h(tanh_fast(acc[i][j][3] + bcol));
                outb[(size_t)(row0 + 0) * Nd + col] = hv.x;
                outb[(size_t)(row0 + 1) * Nd + col] = hv.y;
                outb[(size_t)(row0 + 2) * Nd + col] = hv.z;
                outb[(size_t)(row0 + 3) * Nd + col] = hv.w;
                *(ushort4*)(outbT + (size_t)col * Md + row0) = hv;
            } else if (EPI == 1) {
                ushort4 gv;
#pragma unroll
                for (int r = 0; r < 4; ++r) {
                    size_t idx = (size_t)(row0 + r) * Nd + col;
                    float p = acc[i][j][r] + bias[col];
                    outf[idx] = p;
                    u16 g = f2h(scale * (p - xtgt[idx]));  // scale = raw*2^20
                    outb[idx] = g;
                    ((u16*)&gv)[r] = g;
                }
                *(ushort4*)(outbT + (size_t)col * Md + row0) = gv;
            } else if (EPI == 2) {
                ushort4 dv;
#pragma unroll
                for (int r = 0; r < 4; ++r) {
                    size_t idx = (size_t)(row0 + r) * Nd + col;
                    float tv = h2f(Th[idx]);
                    ((u16*)&dv)[r] = f2h(acc[i][j][r] * (1.0f - tv * tv));
                }
                *(ushort4*)(outbT + (size_t)col * Md + row0) = dv;
            } else {
#pragma unroll
                for (int r = 0; r < 4; ++r)
                    atomicAdd(&outf[(size_t)(row0 + r) * Nd + col], acc[i][j][r]);
            }
        }
    }
}

// ---------------------------------------------------------------------------
// fp32 [R,C] -> optional f16 row-major + optional f16 transposed
// ---------------------------------------------------------------------------
__global__ void k_prep(const float* __restrict__ in, u16* __restrict__ rm,
                       u16* __restrict__ tr, int R, int C) {
    __shared__ float tile[64][65];
    const int tx = threadIdx.x & 63, ty = threadIdx.x >> 6;
    const int c0 = blockIdx.x * 64, r0 = blockIdx.y * 64;
#pragma unroll
    for (int i = 0; i < 64; i += 4) {
        size_t idx = (size_t)(r0 + ty + i) * C + c0 + tx;
        float v = in[idx];
        tile[ty + i][tx] = v;
        if (rm) rm[idx] = f2h(v);
    }
    __syncthreads();
    if (tr) {
#pragma unroll
        for (int i = 0; i < 64; i += 4)
            tr[(size_t)(c0 + ty + i) * R + r0 + tx] = f2h(tile[tx][ty + i]);
    }
}

// row-sum of f16 [R,C] -> fp32 dst[R]; one wave per row
__global__ void k_rowsum(const u16* __restrict__ src, float* __restrict__ dst,
                         int C) {
    const int row = blockIdx.x * 4 + (threadIdx.x >> 6);
    const int lane = threadIdx.x & 63;
    const u16* p = src + (size_t)row * C;
    float s = 0.f;
    for (int c = lane * 8; c < C; c += 64 * 8) {
        s16x8 v = *(const s16x8*)(p + c);
#pragma unroll
        for (int e = 0; e < 8; ++e) s += h2f((u16)v[e]);
    }
#pragma unroll
    for (int off = 32; off; off >>= 1) s += __shfl_down(s, off);
    if (lane == 0) dst[row] = s;
}

// learned-optimizer elementwise update (g is SCALE_G-scaled; invScale folds it)
__global__ void k_update(const float* __restrict__ p, const float* __restrict__ g,
                         float* __restrict__ out, int n,
                         const float* __restrict__ Wm1, const float* __restrict__ bm1,
                         const float* __restrict__ Wm2, const float* __restrict__ bm2,
                         int M, float invScale) {
    __shared__ float s1[64], s2[64], s3[64];
    if (threadIdx.x < M) {
        s1[threadIdx.x] = Wm1[threadIdx.x];
        s2[threadIdx.x] = bm1[threadIdx.x];
        s3[threadIdx.x] = Wm2[threadIdx.x];
    }
    __syncthreads();
    int i = blockIdx.x * blockDim.x + threadIdx.x;
    if (i >= n) return;
    float gv = g[i] * invScale;
    float u = bm2[0];
#pragma unroll 8
    for (int m = 0; m < M; ++m) u += tanh_fast(fmaf(gv, s1[m], s2[m])) * s3[m];
    float pv = p[i];
    out[i] = pv - (LR * u + WD * pv);
}

__global__ void k_zero(float* __restrict__ p, int n) {
    int i = blockIdx.x * blockDim.x + threadIdx.x;
    if (i < n) p[i] = 0.f;
}

extern "C" void kernel_launch(void* const* d_in, const int* in_sizes, int n_in,
                              void* d_out, int out_size, void* d_ws, size_t ws_size,
                              hipStream_t stream) {
    const float* x_t      = (const float*)d_in[0];
    const float* x_target = (const float*)d_in[1];
    const float* w1  = (const float*)d_in[2];
    const float* b1  = (const float*)d_in[3];
    const float* w2  = (const float*)d_in[4];
    const float* b2  = (const float*)d_in[5];
    const float* Wm1 = (const float*)d_in[6];
    const float* bm1 = (const float*)d_in[7];
    const float* Wm2 = (const float*)d_in[8];
    const float* bm2 = (const float*)d_in[9];

    const int H = in_sizes[3];      // 1024
    const int D = in_sizes[5];      // 512
    const int N = in_sizes[0] / D;  // 16384
    const int M = in_sizes[6];      // 32

    // ---- workspace (gw2,gw1 contiguous for single k_zero) ----
    char* w = (char*)d_ws;
    float* gw2 = (float*)w;            w += (size_t)H * D * 4;
    float* gw1 = (float*)w;            w += (size_t)D * H * 4;
    float* gb1 = (float*)w;            w += (size_t)H * 4;
    float* gb2 = (float*)w;            w += (size_t)D * 4;
    u16* Tf   = (u16*)w;               w += (size_t)N * H * 2;  // T f16 rm
    u16* TT   = (u16*)w;               w += (size_t)N * H * 2;  // T^T [H,N]
    u16* dAT  = (u16*)w;               w += (size_t)N * H * 2;  // dA^T [H,N]
    u16* Gb   = (u16*)w;               w += (size_t)N * D * 2;  // G' rm
    u16* GT   = (u16*)w;               w += (size_t)N * D * 2;  // G'^T [D,N]
    u16* xf   = (u16*)w;               w += (size_t)N * D * 2;  // x f16 rm
    u16* xT   = (u16*)w;               w += (size_t)N * D * 2;  // x^T [D,N]
    u16* w1T  = (u16*)w;               w += (size_t)D * H * 2;  // w1^T [H,D]
    u16* w2T  = (u16*)w;               w += (size_t)D * H * 2;  // w2^T [D,H]
    u16* w2b  = (u16*)w;               w += (size_t)H * D * 2;  // w2 rm [H,D]

    float* out  = (float*)d_out;
    float* h_t  = out;                    // [N,D]
    float* o_w1 = h_t + (size_t)N * D;    // [D,H]
    float* o_b1 = o_w1 + (size_t)D * H;   // [H]
    float* o_w2 = o_b1 + H;               // [H,D]
    float* o_b2 = o_w2 + (size_t)H * D;   // [D]

    dim3 blk(NTHREADS);
    const float scaleG = (2.0f / ((float)N * (float)D)) * SCALE_G;

    // zero atomic accumulators (gw2, gw1 contiguous)
    int zn = H * D + D * H;
    k_zero<<<dim3((zn + NTHREADS - 1) / NTHREADS), blk, 0, stream>>>(gw2, zn);

    // input prep: x -> xf + xT ; w1 -> w1T ; w2 -> w2b + w2T
    k_prep<<<dim3(D / 64, N / 64), blk, 0, stream>>>(x_t, xf, xT, N, D);
    k_prep<<<dim3(H / 64, D / 64), blk, 0, stream>>>(w1, nullptr, w1T, D, H);
    k_prep<<<dim3(D / 64, H / 64), blk, 0, stream>>>(w2, w2b, w2T, H, D);

    // fwd1: T = tanh(x@w1 + b1) -> Tf + TT
    k_mfma<0><<<dim3((H / 128) * (N / 128), 1), blk, 0, stream>>>(
        xf, w1T, H / 128, N, H, D, D, b1, nullptr, nullptr,
        nullptr, Tf, TT, 0.f);

    // fwd2: h = T@w2 + b2 (fp32) ; G' = scaleG*(h - xtgt) -> Gb + GT
    k_mfma<1><<<dim3((D / 128) * (N / 128), 1), blk, 0, stream>>>(
        Tf, w2T, D / 128, N, D, H, H, b2, x_target, nullptr,
        h_t, Gb, GT, scaleG);

    // dA' = (G' @ w2^T) * (1 - T^2) -> dAT
    k_mfma<2><<<dim3((H / 128) * (N / 128), 1), blk, 0, stream>>>(
        Gb, w2b, H / 128, N, H, D, D, nullptr, nullptr, Tf,
        nullptr, nullptr, dAT, 0.f);

    // gw2' = T^T @ G'  [H,D]: A=TT[H,N], Bt=GT[D,N], split-K, atomics
    const int SPLIT = 16;
    k_mfma<3><<<dim3((D / 128) * (H / 128), SPLIT), blk, 0, stream>>>(
        TT, GT, D / 128, H, D, N, N / SPLIT, nullptr, nullptr, nullptr,
        gw2, nullptr, nullptr, 0.f);

    // gw1' = x^T @ dA'  [D,H]: A=xT[D,N], Bt=dAT[H,N]
    k_mfma<3><<<dim3((H / 128) * (D / 128), SPLIT), blk, 0, stream>>>(
        xT, dAT, H / 128, D, H, N, N / SPLIT, nullptr, nullptr, nullptr,
        gw1, nullptr, nullptr, 0.f);

    // bias grads: row-sums of transposed buffers (coalesced, no atomics)
    k_rowsum<<<dim3(H / 4), blk, 0, stream>>>(dAT, gb1, N);
    k_rowsum<<<dim3(D / 4), blk, 0, stream>>>(GT, gb2, N);

    // learned-optimizer updates (invScale folds the 2^20 grad scaling)
    k_update<<<dim3((D * H + NTHREADS - 1) / NTHREADS), blk, 0, stream>>>(
        w1, gw1, o_w1, D * H, Wm1, bm1, Wm2, bm2, M, INV_SCALE_G);
    k_update<<<dim3((H + NTHREADS - 1) / NTHREADS), blk, 0, stream>>>(
        b1, gb1, o_b1, H, Wm1, bm1, Wm2, bm2, M, INV_SCALE_G);
    k_update<<<dim3((H * D + NTHREADS - 1) / NTHREADS), blk, 0, stream>>>(
        w2, gw2, o_w2, H * D, Wm1, bm1, Wm2, bm2, M, INV_SCALE_G);
    k_update<<<dim3((D + NTHREADS - 1) / NTHREADS), blk, 0, stream>>>(
        b2, gb2, o_b2, D, Wm1, bm1, Wm2, bm2, M, INV_SCALE_G);
}

// Round 6
// 398.374 us; speedup vs baseline: 4.7707x; 1.0593x over previous
//
#include <hip/hip_runtime.h>
#include <hip/hip_bf16.h>

#define LR 0.01f
#define WD 0.01f
#define NTHREADS 256
#define SCALE_G 1048576.0f      // 2^20: lift G out of f16-subnormal range
#define INV_SCALE_G 9.5367431640625e-07f  // 2^-20

typedef short s16x8 __attribute__((ext_vector_type(8)));
typedef _Float16 f16x8 __attribute__((ext_vector_type(8)));
typedef float f32x4 __attribute__((ext_vector_type(4)));
typedef unsigned short u16;

__device__ __forceinline__ u16 f2h(float f) {
    _Float16 h = (_Float16)f;
    return *reinterpret_cast<u16*>(&h);
}
__device__ __forceinline__ float h2f(u16 u) {
    _Float16 h;
    *reinterpret_cast<u16*>(&h) = u;
    return (float)h;
}
// fast tanh: 1 - 2/(exp(2x)+1), clamped; ~1e-6 error
__device__ __forceinline__ float tanh_fast(float x) {
    float t = fminf(fmaxf(2.f * x, -30.f), 30.f);
    float e = __expf(t);
    return 1.f - 2.f * __builtin_amdgcn_rcpf(e + 1.f);
}

// ---------------------------------------------------------------------------
// Stage a paired tile [128 rows][A-chunks 0..3 | B-chunks 4..7] (128B rows)
// into linear LDS with XOR swizzle chl = chp ^ (row&7) applied on the GLOBAL
// source (rule #21). 4 global_load_lds instructions per wave -> vmcnt +4.
// ---------------------------------------------------------------------------
__device__ __forceinline__ void stage_pair(const u16* gA, const u16* gB, int ldg,
                                           u16* lds) {
    const int t = threadIdx.x;
#pragma unroll
    for (int q = 0; q < 4; ++q) {
        int s = t + q * 256;
        int row = s >> 3, chp = s & 7;
        int chl = chp ^ (row & 7);
        const u16* gp = (chl < 4) ? (gA + (size_t)row * ldg + chl * 8)
                                  : (gB + (size_t)row * ldg + (chl & 3) * 8);
        __builtin_amdgcn_global_load_lds(
            (const __attribute__((address_space(1))) void*)gp,
            (__attribute__((address_space(3))) void*)(lds + s * 8), 16, 0, 0);
    }
}

// swizzled fragment read: logical chunk c (A: 0..3, B: 4..7) of row r
__device__ __forceinline__ f16x8 frag(const u16* P, int r, int c) {
    return *(const f16x8*)(P + r * 64 + ((c ^ (r & 7)) * 8));
}

// ---------------------------------------------------------------------------
// MFMA GEMM: C[M,N] = A[M,K] @ Bt[N,K]^T, f16 in, fp32 accum.
// 128x128 tile, BK=32, 4 waves. 2-deep pipeline with COUNTED vmcnt (T4):
// prologue stages tiles 0,1; per iter: wait vmcnt(4) (tile t only, never 0
// mid-loop) + s_barrier -> ds_read+MFMA -> s_barrier -> refill buffer with
// tile t+2. XCD-aware block swizzle (T1). setprio around MFMA (T5).
// EPI: 0 tanh->T(rm)+TT ; 1 h_t(fp32)+G'(rm)+GT'+gb2-colsum ;
//      2 dtanh->dAT+gb1-colsum ; 3 atomicAdd fp32 (split-K weight grads)
// ---------------------------------------------------------------------------
template <int EPI>
__global__ __launch_bounds__(NTHREADS) void k_mfma(
    const u16* __restrict__ A, const u16* __restrict__ Bt,
    int nbx, int Md, int Nd, int Kd, int Kslice,
    const float* __restrict__ bias, const float* __restrict__ xtgt,
    const u16* __restrict__ Th,
    float* __restrict__ outf, u16* __restrict__ outb, u16* __restrict__ outbT,
    float* __restrict__ gbias, float scale) {
    __shared__ u16 smem[2 * 8192];
    __shared__ float colacc[128];

    // XCD swizzle (all grids have nwg % 8 == 0)
    const int nwg = gridDim.x;
    const int sw = (blockIdx.x & 7) * (nwg >> 3) + (blockIdx.x >> 3);
    const int m0 = (sw / nbx) * 128, n0 = (sw % nbx) * 128;
    const int kb = blockIdx.y * Kslice;

    const int lane = threadIdx.x & 63, wid = threadIdx.x >> 6;
    const int wrow = (wid >> 1) * 64, wcol = (wid & 1) * 64;
    const int lm = lane & 15;
    const int cA = lane >> 4;

    f32x4 acc[4][4] = {};

    const u16* gA = A + (size_t)m0 * Kd + kb;
    const u16* gB = Bt + (size_t)n0 * Kd + kb;
    const int nt = Kslice >> 5;  // K-tiles of 32; always >= 16 here

    if (EPI == 1 || EPI == 2)
        if (threadIdx.x < 128) colacc[threadIdx.x] = 0.f;

    // prologue: stage tiles 0 and 1 (8 outstanding vmem per wave)
    stage_pair(gA, gB, Kd, smem);
    stage_pair(gA + 32, gB + 32, Kd, smem + 8192);

    int cur = 0;
    for (int t = 0; t < nt; ++t, cur ^= 1) {
        // wait only for tile t's 4 loads (oldest); keep tile t+1's in flight
        if (t + 1 < nt) asm volatile("s_waitcnt vmcnt(4)" ::: "memory");
        else            asm volatile("s_waitcnt vmcnt(0)" ::: "memory");
        __builtin_amdgcn_s_barrier();  // all waves' tile-t loads landed

        const u16* P1 = smem + cur * 8192;
        f16x8 a[4], b[4];
#pragma unroll
        for (int i = 0; i < 4; ++i) {
            a[i] = frag(P1, wrow + i * 16 + lm, cA);
            b[i] = frag(P1, wcol + i * 16 + lm, cA + 4);
        }
        __builtin_amdgcn_s_setprio(1);
#pragma unroll
        for (int i = 0; i < 4; ++i)
#pragma unroll
            for (int j = 0; j < 4; ++j)
                acc[i][j] = __builtin_amdgcn_mfma_f32_16x16x32_f16(
                    a[i], b[j], acc[i][j], 0, 0, 0);
        __builtin_amdgcn_s_setprio(0);

        asm volatile("" ::: "memory");   // pin ds_reads before the barrier
        __builtin_amdgcn_s_barrier();    // all waves done reading buf[cur]
        if (t + 2 < nt)
            stage_pair(gA + (t + 2) * 32, gB + (t + 2) * 32, Kd,
                       smem + cur * 8192);  // refill consumed buffer
    }

    // C/D layout (m89): col = lane&15, row = (lane>>4)*4 + reg
    const int rbase = (lane >> 4) * 4;
#pragma unroll
    for (int i = 0; i < 4; ++i) {
        const int row0 = m0 + wrow + i * 16 + rbase;
#pragma unroll
        for (int j = 0; j < 4; ++j) {
            const int col = n0 + wcol + j * 16 + lm;
            if (EPI == 0) {
                ushort4 hv;
                float bcol = bias[col];
                hv.x = f2h(tanh_fast(acc[i][j][0] + bcol));
                hv.y = f2h(tanh_fast(acc[i][j][1] + bcol));
                hv.z = f2h(tanh_fast(acc[i][j][2] + bcol));
                hv.w = f2h(tanh_fast(acc[i][j][3] + bcol));
                outb[(size_t)(row0 + 0) * Nd + col] = hv.x;
                outb[(size_t)(row0 + 1) * Nd + col] = hv.y;
                outb[(size_t)(row0 + 2) * Nd + col] = hv.z;
                outb[(size_t)(row0 + 3) * Nd + col] = hv.w;
                *(ushort4*)(outbT + (size_t)col * Md + row0) = hv;
            } else if (EPI == 1) {
                ushort4 gv;
                float csum = 0.f;
#pragma unroll
                for (int r = 0; r < 4; ++r) {
                    size_t idx = (size_t)(row0 + r) * Nd + col;
                    float p = acc[i][j][r] + bias[col];
                    outf[idx] = p;
                    float gf = scale * (p - xtgt[idx]);  // scale = raw*2^20
                    csum += gf;
                    u16 g = f2h(gf);
                    outb[idx] = g;
                    ((u16*)&gv)[r] = g;
                }
                *(ushort4*)(outbT + (size_t)col * Md + row0) = gv;
                atomicAdd(&colacc[wcol + j * 16 + lm], csum);
            } else if (EPI == 2) {
                ushort4 dv;
                float csum = 0.f;
#pragma unroll
                for (int r = 0; r < 4; ++r) {
                    size_t idx = (size_t)(row0 + r) * Nd + col;
                    float tv = h2f(Th[idx]);
                    float da = acc[i][j][r] * (1.0f - tv * tv);
                    csum += da;
                    ((u16*)&dv)[r] = f2h(da);
                }
                *(ushort4*)(outbT + (size_t)col * Md + row0) = dv;
                atomicAdd(&colacc[wcol + j * 16 + lm], csum);
            } else {
#pragma unroll
                for (int r = 0; r < 4; ++r)
                    atomicAdd(&outf[(size_t)(row0 + r) * Nd + col], acc[i][j][r]);
            }
        }
    }
    if (EPI == 1 || EPI == 2) {
        __syncthreads();
        if (threadIdx.x < 128)
            atomicAdd(&gbias[n0 + threadIdx.x], colacc[threadIdx.x]);
    }
}

// ---------------------------------------------------------------------------
// fp32 [R,C] -> optional f16 row-major + optional f16 transposed
// ---------------------------------------------------------------------------
__global__ void k_prep(const float* __restrict__ in, u16* __restrict__ rm,
                       u16* __restrict__ tr, int R, int C) {
    __shared__ float tile[64][65];
    const int tx = threadIdx.x & 63, ty = threadIdx.x >> 6;
    const int c0 = blockIdx.x * 64, r0 = blockIdx.y * 64;
#pragma unroll
    for (int i = 0; i < 64; i += 4) {
        size_t idx = (size_t)(r0 + ty + i) * C + c0 + tx;
        float v = in[idx];
        tile[ty + i][tx] = v;
        if (rm) rm[idx] = f2h(v);
    }
    __syncthreads();
    if (tr) {
#pragma unroll
        for (int i = 0; i < 64; i += 4)
            tr[(size_t)(c0 + ty + i) * R + r0 + tx] = f2h(tile[tx][ty + i]);
    }
}

// merged learned-optimizer update over all four params (grads contiguous in
// output order: gw1 | gb1 | gw2 | gb2 ; outputs o_w1|o_b1|o_w2|o_b2 contig)
__global__ void k_update_all(
    const float* __restrict__ w1, const float* __restrict__ b1,
    const float* __restrict__ w2, const float* __restrict__ b2,
    const float* __restrict__ g, float* __restrict__ out,
    int n1, int n2, int n3, int n4,
    const float* __restrict__ Wm1, const float* __restrict__ bm1,
    const float* __restrict__ Wm2, const float* __restrict__ bm2,
    int M, float invScale) {
    __shared__ float s1[64], s2[64], s3[64];
    if (threadIdx.x < M) {
        s1[threadIdx.x] = Wm1[threadIdx.x];
        s2[threadIdx.x] = bm1[threadIdx.x];
        s3[threadIdx.x] = Wm2[threadIdx.x];
    }
    __syncthreads();
    int i = blockIdx.x * blockDim.x + threadIdx.x;
    int n = n1 + n2 + n3 + n4;
    if (i >= n) return;
    const float* p;
    int off;
    if (i < n1) { p = w1; off = 0; }
    else if (i < n1 + n2) { p = b1; off = n1; }
    else if (i < n1 + n2 + n3) { p = w2; off = n1 + n2; }
    else { p = b2; off = n1 + n2 + n3; }
    float gv = g[i] * invScale;
    float u = bm2[0];
#pragma unroll 8
    for (int m = 0; m < M; ++m) u += tanh_fast(fmaf(gv, s1[m], s2[m])) * s3[m];
    float pv = p[i - off];
    out[i] = pv - (LR * u + WD * pv);
}

__global__ void k_zero(float* __restrict__ p, int n) {
    int i = blockIdx.x * blockDim.x + threadIdx.x;
    if (i < n) p[i] = 0.f;
}

extern "C" void kernel_launch(void* const* d_in, const int* in_sizes, int n_in,
                              void* d_out, int out_size, void* d_ws, size_t ws_size,
                              hipStream_t stream) {
    const float* x_t      = (const float*)d_in[0];
    const float* x_target = (const float*)d_in[1];
    const float* w1  = (const float*)d_in[2];
    const float* b1  = (const float*)d_in[3];
    const float* w2  = (const float*)d_in[4];
    const float* b2  = (const float*)d_in[5];
    const float* Wm1 = (const float*)d_in[6];
    const float* bm1 = (const float*)d_in[7];
    const float* Wm2 = (const float*)d_in[8];
    const float* bm2 = (const float*)d_in[9];

    const int H = in_sizes[3];      // 1024
    const int D = in_sizes[5];      // 512
    const int N = in_sizes[0] / D;  // 16384
    const int M = in_sizes[6];      // 32

    // ---- workspace: grads FIRST, contiguous in OUTPUT order ----
    char* w = (char*)d_ws;
    float* gw1 = (float*)w;            w += (size_t)D * H * 4;  // [D,H]
    float* gb1 = (float*)w;            w += (size_t)H * 4;
    float* gw2 = (float*)w;            w += (size_t)H * D * 4;  // [H,D]
    float* gb2 = (float*)w;            w += (size_t)D * 4;
    u16* Tf   = (u16*)w;               w += (size_t)N * H * 2;  // T f16 rm
    u16* TT   = (u16*)w;               w += (size_t)N * H * 2;  // T^T [H,N]
    u16* dAT  = (u16*)w;               w += (size_t)N * H * 2;  // dA^T [H,N]
    u16* Gb   = (u16*)w;               w += (size_t)N * D * 2;  // G' rm
    u16* GT   = (u16*)w;               w += (size_t)N * D * 2;  // G'^T [D,N]
    u16* xf   = (u16*)w;               w += (size_t)N * D * 2;  // x f16 rm
    u16* xT   = (u16*)w;               w += (size_t)N * D * 2;  // x^T [D,N]
    u16* w1T  = (u16*)w;               w += (size_t)D * H * 2;  // w1^T [H,D]
    u16* w2T  = (u16*)w;               w += (size_t)D * H * 2;  // w2^T [D,H]
    u16* w2b  = (u16*)w;               w += (size_t)H * D * 2;  // w2 rm [H,D]

    float* out  = (float*)d_out;
    float* h_t  = out;                    // [N,D]
    float* o_w1 = h_t + (size_t)N * D;    // [D,H] (updates contiguous from here)

    dim3 blk(NTHREADS);
    const float scaleG = (2.0f / ((float)N * (float)D)) * SCALE_G;

    // zero all atomic accumulators (gw1,gb1,gw2,gb2 contiguous)
    int zn = D * H + H + H * D + D;
    k_zero<<<dim3((zn + NTHREADS - 1) / NTHREADS), blk, 0, stream>>>(gw1, zn);

    // input prep: x -> xf + xT ; w1 -> w1T ; w2 -> w2b + w2T
    k_prep<<<dim3(D / 64, N / 64), blk, 0, stream>>>(x_t, xf, xT, N, D);
    k_prep<<<dim3(H / 64, D / 64), blk, 0, stream>>>(w1, nullptr, w1T, D, H);
    k_prep<<<dim3(D / 64, H / 64), blk, 0, stream>>>(w2, w2b, w2T, H, D);

    // fwd1: T = tanh(x@w1 + b1) -> Tf + TT
    k_mfma<0><<<dim3((H / 128) * (N / 128), 1), blk, 0, stream>>>(
        xf, w1T, H / 128, N, H, D, D, b1, nullptr, nullptr,
        nullptr, Tf, TT, nullptr, 0.f);

    // fwd2: h = T@w2 + b2 (fp32) ; G' = scaleG*(h - xtgt) -> Gb + GT + gb2
    k_mfma<1><<<dim3((D / 128) * (N / 128), 1), blk, 0, stream>>>(
        Tf, w2T, D / 128, N, D, H, H, b2, x_target, nullptr,
        h_t, Gb, GT, gb2, scaleG);

    // dA' = (G' @ w2^T) * (1 - T^2) -> dAT + gb1
    k_mfma<2><<<dim3((H / 128) * (N / 128), 1), blk, 0, stream>>>(
        Gb, w2b, H / 128, N, H, D, D, nullptr, nullptr, Tf,
        nullptr, nullptr, dAT, gb1, 0.f);

    // gw2' = T^T @ G'  [H,D]: A=TT[H,N], Bt=GT[D,N], split-K, atomics
    const int SPLIT = 16;
    k_mfma<3><<<dim3((D / 128) * (H / 128), SPLIT), blk, 0, stream>>>(
        TT, GT, D / 128, H, D, N, N / SPLIT, nullptr, nullptr, nullptr,
        gw2, nullptr, nullptr, nullptr, 0.f);

    // gw1' = x^T @ dA'  [D,H]: A=xT[D,N], Bt=dAT[H,N]
    k_mfma<3><<<dim3((H / 128) * (D / 128), SPLIT), blk, 0, stream>>>(
        xT, dAT, H / 128, D, H, N, N / SPLIT, nullptr, nullptr, nullptr,
        gw1, nullptr, nullptr, nullptr, 0.f);

    // merged learned-optimizer update (grads gw1|gb1|gw2|gb2 contiguous)
    int nAll = D * H + H + H * D + D;
    k_update_all<<<dim3((nAll + NTHREADS - 1) / NTHREADS), blk, 0, stream>>>(
        w1, b1, w2, b2, gw1, o_w1, D * H, H, H * D, D,
        Wm1, bm1, Wm2, bm2, M, INV_SCALE_G);
}

// Round 7
// 380.778 us; speedup vs baseline: 4.9912x; 1.0462x over previous
//
#include <hip/hip_runtime.h>
#include <hip/hip_bf16.h>

#define LR 0.01f
#define WD 0.01f
#define NTHREADS 256
#define SCALE_G 1048576.0f      // 2^20: lift G out of f16-subnormal range
#define INV_SCALE_G 9.5367431640625e-07f  // 2^-20
#define TRS 136                 // padded LDS stride (u16) for transpose image

typedef short s16x8 __attribute__((ext_vector_type(8)));
typedef _Float16 f16x8 __attribute__((ext_vector_type(8)));
typedef float f32x4 __attribute__((ext_vector_type(4)));
typedef unsigned short u16;

__device__ __forceinline__ u16 f2h(float f) {
    _Float16 h = (_Float16)f;
    return *reinterpret_cast<u16*>(&h);
}
__device__ __forceinline__ float h2f(u16 u) {
    _Float16 h;
    *reinterpret_cast<u16*>(&h) = u;
    return (float)h;
}
// fast tanh: 1 - 2/(exp(2x)+1), clamped; ~1e-6 error
__device__ __forceinline__ float tanh_fast(float x) {
    float t = fminf(fmaxf(2.f * x, -30.f), 30.f);
    float e = __expf(t);
    return 1.f - 2.f * __builtin_amdgcn_rcpf(e + 1.f);
}

// ---------------------------------------------------------------------------
// Stage a paired tile [128 rows][A-chunks 0..3 | B-chunks 4..7] (128B rows)
// into linear LDS with XOR swizzle chl = chp ^ (row&7) applied on the GLOBAL
// source (rule #21). 1024 slots of 16B, 4 issues per 256 threads.
// ---------------------------------------------------------------------------
__device__ __forceinline__ void stage_pair(const u16* gA, const u16* gB, int ldg,
                                           u16* lds) {
    const int t = threadIdx.x;
#pragma unroll
    for (int q = 0; q < 4; ++q) {
        int s = t + q * 256;
        int row = s >> 3, chp = s & 7;
        int chl = chp ^ (row & 7);
        const u16* gp = (chl < 4) ? (gA + (size_t)row * ldg + chl * 8)
                                  : (gB + (size_t)row * ldg + (chl & 3) * 8);
        __builtin_amdgcn_global_load_lds(
            (const __attribute__((address_space(1))) void*)gp,
            (__attribute__((address_space(3))) void*)(lds + s * 8), 16, 0, 0);
    }
}

// swizzled fragment read: logical chunk c (A: 0..3, B: 4..7) of row r
__device__ __forceinline__ f16x8 frag(const u16* P, int r, int c) {
    return *(const f16x8*)(P + r * 64 + ((c ^ (r & 7)) * 8));
}

// ---------------------------------------------------------------------------
// MFMA GEMM: C[M,N] = A[M,K] @ Bt[N,K]^T, f16 in, fp32 accum.
// 128x128 tile, BK=32, 4 waves, 2-buffer staging (round-5 proven loop),
// XCD-aware block swizzle. Epilogue does all f16 output stores COALESCED via
// an LDS transpose round-trip (staging LDS reused, pad stride 136).
// EPI: 0 tanh -> Tf(rm) + TT(tr)
//      1 h_t(fp32 rm, direct) + G'(rm) + GT'(tr) + gb2 colsum
//      2 dtanh -> dAT(tr only) + gb1 colsum
//      3 atomicAdd fp32 (split-K weight grads)
// ---------------------------------------------------------------------------
template <int EPI>
__global__ __launch_bounds__(NTHREADS) void k_mfma(
    const u16* __restrict__ A, const u16* __restrict__ Bt,
    int nbx, int Md, int Nd, int Kd, int Kslice,
    const float* __restrict__ bias, const float* __restrict__ xtgt,
    const u16* __restrict__ Th,
    float* __restrict__ outf, u16* __restrict__ outb, u16* __restrict__ outbT,
    float* __restrict__ gbias, float scale) {
    __shared__ u16 smem[128 * TRS];   // staging (2x8192=16384) and tr image share
    __shared__ float colacc[128];

    // XCD swizzle (all grids have nwg % 8 == 0)
    const int nwg = gridDim.x;
    const int sw = (blockIdx.x & 7) * (nwg >> 3) + (blockIdx.x >> 3);
    const int m0 = (sw / nbx) * 128, n0 = (sw % nbx) * 128;
    const int kb = blockIdx.y * Kslice;

    const int lane = threadIdx.x & 63, wid = threadIdx.x >> 6;
    const int wrow = (wid >> 1) * 64, wcol = (wid & 1) * 64;
    const int lm = lane & 15;
    const int cA = lane >> 4;

    f32x4 acc[4][4] = {};

    const u16* gA = A + (size_t)m0 * Kd + kb;
    const u16* gB = Bt + (size_t)n0 * Kd + kb;

    if (EPI == 1 || EPI == 2)
        if (threadIdx.x < 128) colacc[threadIdx.x] = 0.f;

    stage_pair(gA, gB, Kd, smem);
    __syncthreads();  // prologue drain: buf0 ready

    int cur = 0;
    for (int k0 = 0; k0 < Kslice; k0 += 32, cur ^= 1) {
        if (k0 + 32 < Kslice)
            stage_pair(gA + k0 + 32, gB + k0 + 32, Kd, smem + (cur ^ 1) * 8192);
        const u16* P1 = smem + cur * 8192;
        f16x8 a[4], b[4];
#pragma unroll
        for (int i = 0; i < 4; ++i) {
            a[i] = frag(P1, wrow + i * 16 + lm, cA);
            b[i] = frag(P1, wcol + i * 16 + lm, cA + 4);
        }
#pragma unroll
        for (int i = 0; i < 4; ++i)
#pragma unroll
            for (int j = 0; j < 4; ++j)
                acc[i][j] = __builtin_amdgcn_mfma_f32_16x16x32_f16(
                    a[i], b[j], acc[i][j], 0, 0, 0);
        __syncthreads();  // drains prefetch + guards buffer swap
    }
    // all waves past final barrier: staging LDS is dead, reusable.

    // C/D layout (m89): col = lane&15, row = (lane>>4)*4 + reg
    const int rbase = (lane >> 4) * 4;

    if (EPI == 3) {
#pragma unroll
        for (int i = 0; i < 4; ++i) {
            const int row0 = m0 + wrow + i * 16 + rbase;
#pragma unroll
            for (int j = 0; j < 4; ++j) {
                const int col = n0 + wcol + j * 16 + lm;
#pragma unroll
                for (int r = 0; r < 4; ++r)
                    atomicAdd(&outf[(size_t)(row0 + r) * Nd + col], acc[i][j][r]);
            }
        }
        return;
    }

    // ---- compute f16 payload hv[i][j] + direct fp32 outputs + colsums ----
    ushort4 hv[4][4];
#pragma unroll
    for (int i = 0; i < 4; ++i) {
        const int row0 = m0 + wrow + i * 16 + rbase;
#pragma unroll
        for (int j = 0; j < 4; ++j) {
            const int col = n0 + wcol + j * 16 + lm;
            if (EPI == 0) {
                float bcol = bias[col];
                hv[i][j].x = f2h(tanh_fast(acc[i][j][0] + bcol));
                hv[i][j].y = f2h(tanh_fast(acc[i][j][1] + bcol));
                hv[i][j].z = f2h(tanh_fast(acc[i][j][2] + bcol));
                hv[i][j].w = f2h(tanh_fast(acc[i][j][3] + bcol));
            } else if (EPI == 1) {
                float csum = 0.f;
                float bcol = bias[col];
#pragma unroll
                for (int r = 0; r < 4; ++r) {
                    size_t idx = (size_t)(row0 + r) * Nd + col;
                    float p = acc[i][j][r] + bcol;
                    outf[idx] = p;   // h_t fp32: 16 lanes x 4B = full 64B lines
                    float gf = scale * (p - xtgt[idx]);  // scale = raw*2^20
                    csum += gf;
                    ((u16*)&hv[i][j])[r] = f2h(gf);
                }
                atomicAdd(&colacc[wcol + j * 16 + lm], csum);
            } else {  // EPI == 2
                float csum = 0.f;
#pragma unroll
                for (int r = 0; r < 4; ++r) {
                    size_t idx = (size_t)(row0 + r) * Nd + col;
                    float tv = h2f(Th[idx]);
                    float da = acc[i][j][r] * (1.0f - tv * tv);
                    csum += da;
                    ((u16*)&hv[i][j])[r] = f2h(da);
                }
                atomicAdd(&colacc[wcol + j * 16 + lm], csum);
            }
        }
    }

    // ---- pass A: transposed output via LDS [col][row] image (stride TRS) ----
#pragma unroll
    for (int i = 0; i < 4; ++i)
#pragma unroll
        for (int j = 0; j < 4; ++j)
            *(ushort4*)(smem + (wcol + j * 16 + lm) * TRS + (wrow + i * 16 + rbase)) =
                hv[i][j];
    __syncthreads();
#pragma unroll
    for (int p = 0; p < 8; ++p) {
        int tr = wid * 32 + p * 4 + (lane >> 4);  // tr row = C col
        int ch = lane & 15;
        s16x8 v = *(const s16x8*)(smem + tr * TRS + ch * 8);
        *(s16x8*)(outbT + (size_t)(n0 + tr) * Md + m0 + ch * 8) = v;
    }

    // ---- pass B: row-major f16 output via LDS [row][col] image ----
    if (EPI <= 1) {
        __syncthreads();  // pass-A LDS reads done before overwrite
#pragma unroll
        for (int i = 0; i < 4; ++i)
#pragma unroll
            for (int j = 0; j < 4; ++j)
#pragma unroll
                for (int r = 0; r < 4; ++r)
                    smem[(wrow + i * 16 + rbase + r) * TRS + wcol + j * 16 + lm] =
                        ((u16*)&hv[i][j])[r];
        __syncthreads();
#pragma unroll
        for (int p = 0; p < 8; ++p) {
            int rr = wid * 32 + p * 4 + (lane >> 4);
            int ch = lane & 15;
            s16x8 v = *(const s16x8*)(smem + rr * TRS + ch * 8);
            *(s16x8*)(outb + (size_t)(m0 + rr) * Nd + n0 + ch * 8) = v;
        }
    }

    if (EPI == 1 || EPI == 2) {
        __syncthreads();
        if (threadIdx.x < 128)
            atomicAdd(&gbias[n0 + threadIdx.x], colacc[threadIdx.x]);
    }
}

// ---------------------------------------------------------------------------
// fp32 [R,C] -> optional f16 row-major + optional f16 transposed
// ---------------------------------------------------------------------------
__global__ void k_prep(const float* __restrict__ in, u16* __restrict__ rm,
                       u16* __restrict__ tr, int R, int C) {
    __shared__ float tile[64][65];
    const int tx = threadIdx.x & 63, ty = threadIdx.x >> 6;
    const int c0 = blockIdx.x * 64, r0 = blockIdx.y * 64;
#pragma unroll
    for (int i = 0; i < 64; i += 4) {
        size_t idx = (size_t)(r0 + ty + i) * C + c0 + tx;
        float v = in[idx];
        tile[ty + i][tx] = v;
        if (rm) rm[idx] = f2h(v);
    }
    __syncthreads();
    if (tr) {
#pragma unroll
        for (int i = 0; i < 64; i += 4)
            tr[(size_t)(c0 + ty + i) * R + r0 + tx] = f2h(tile[tx][ty + i]);
    }
}

// merged learned-optimizer update (grads contiguous gw1|gb1|gw2|gb2)
__global__ void k_update_all(
    const float* __restrict__ w1, const float* __restrict__ b1,
    const float* __restrict__ w2, const float* __restrict__ b2,
    const float* __restrict__ g, float* __restrict__ out,
    int n1, int n2, int n3, int n4,
    const float* __restrict__ Wm1, const float* __restrict__ bm1,
    const float* __restrict__ Wm2, const float* __restrict__ bm2,
    int M, float invScale) {
    __shared__ float s1[64], s2[64], s3[64];
    if (threadIdx.x < M) {
        s1[threadIdx.x] = Wm1[threadIdx.x];
        s2[threadIdx.x] = bm1[threadIdx.x];
        s3[threadIdx.x] = Wm2[threadIdx.x];
    }
    __syncthreads();
    int i = blockIdx.x * blockDim.x + threadIdx.x;
    int n = n1 + n2 + n3 + n4;
    if (i >= n) return;
    const float* p;
    int off;
    if (i < n1) { p = w1; off = 0; }
    else if (i < n1 + n2) { p = b1; off = n1; }
    else if (i < n1 + n2 + n3) { p = w2; off = n1 + n2; }
    else { p = b2; off = n1 + n2 + n3; }
    float gv = g[i] * invScale;
    float u = bm2[0];
#pragma unroll 8
    for (int m = 0; m < M; ++m) u += tanh_fast(fmaf(gv, s1[m], s2[m])) * s3[m];
    float pv = p[i - off];
    out[i] = pv - (LR * u + WD * pv);
}

__global__ void k_zero(float* __restrict__ p, int n) {
    int i = blockIdx.x * blockDim.x + threadIdx.x;
    if (i < n) p[i] = 0.f;
}

extern "C" void kernel_launch(void* const* d_in, const int* in_sizes, int n_in,
                              void* d_out, int out_size, void* d_ws, size_t ws_size,
                              hipStream_t stream) {
    const float* x_t      = (const float*)d_in[0];
    const float* x_target = (const float*)d_in[1];
    const float* w1  = (const float*)d_in[2];
    const float* b1  = (const float*)d_in[3];
    const float* w2  = (const float*)d_in[4];
    const float* b2  = (const float*)d_in[5];
    const float* Wm1 = (const float*)d_in[6];
    const float* bm1 = (const float*)d_in[7];
    const float* Wm2 = (const float*)d_in[8];
    const float* bm2 = (const float*)d_in[9];

    const int H = in_sizes[3];      // 1024
    const int D = in_sizes[5];      // 512
    const int N = in_sizes[0] / D;  // 16384
    const int M = in_sizes[6];      // 32

    // ---- workspace: grads FIRST, contiguous in OUTPUT order ----
    char* w = (char*)d_ws;
    float* gw1 = (float*)w;            w += (size_t)D * H * 4;  // [D,H]
    float* gb1 = (float*)w;            w += (size_t)H * 4;
    float* gw2 = (float*)w;            w += (size_t)H * D * 4;  // [H,D]
    float* gb2 = (float*)w;            w += (size_t)D * 4;
    u16* Tf   = (u16*)w;               w += (size_t)N * H * 2;  // T f16 rm
    u16* TT   = (u16*)w;               w += (size_t)N * H * 2;  // T^T [H,N]
    u16* dAT  = (u16*)w;               w += (size_t)N * H * 2;  // dA^T [H,N]
    u16* Gb   = (u16*)w;               w += (size_t)N * D * 2;  // G' rm
    u16* GT   = (u16*)w;               w += (size_t)N * D * 2;  // G'^T [D,N]
    u16* xf   = (u16*)w;               w += (size_t)N * D * 2;  // x f16 rm
    u16* xT   = (u16*)w;               w += (size_t)N * D * 2;  // x^T [D,N]
    u16* w1T  = (u16*)w;               w += (size_t)D * H * 2;  // w1^T [H,D]
    u16* w2T  = (u16*)w;               w += (size_t)D * H * 2;  // w2^T [D,H]
    u16* w2b  = (u16*)w;               w += (size_t)H * D * 2;  // w2 rm [H,D]

    float* out  = (float*)d_out;
    float* h_t  = out;                    // [N,D]
    float* o_w1 = h_t + (size_t)N * D;    // [D,H] (updates contiguous from here)

    dim3 blk(NTHREADS);
    const float scaleG = (2.0f / ((float)N * (float)D)) * SCALE_G;

    // zero all atomic accumulators (gw1,gb1,gw2,gb2 contiguous)
    int zn = D * H + H + H * D + D;
    k_zero<<<dim3((zn + NTHREADS - 1) / NTHREADS), blk, 0, stream>>>(gw1, zn);

    // input prep: x -> xf + xT ; w1 -> w1T ; w2 -> w2b + w2T
    k_prep<<<dim3(D / 64, N / 64), blk, 0, stream>>>(x_t, xf, xT, N, D);
    k_prep<<<dim3(H / 64, D / 64), blk, 0, stream>>>(w1, nullptr, w1T, D, H);
    k_prep<<<dim3(D / 64, H / 64), blk, 0, stream>>>(w2, w2b, w2T, H, D);

    // fwd1: T = tanh(x@w1 + b1) -> Tf + TT
    k_mfma<0><<<dim3((H / 128) * (N / 128), 1), blk, 0, stream>>>(
        xf, w1T, H / 128, N, H, D, D, b1, nullptr, nullptr,
        nullptr, Tf, TT, nullptr, 0.f);

    // fwd2: h = T@w2 + b2 (fp32) ; G' = scaleG*(h - xtgt) -> Gb + GT + gb2
    k_mfma<1><<<dim3((D / 128) * (N / 128), 1), blk, 0, stream>>>(
        Tf, w2T, D / 128, N, D, H, H, b2, x_target, nullptr,
        h_t, Gb, GT, gb2, scaleG);

    // dA' = (G' @ w2^T) * (1 - T^2) -> dAT + gb1
    k_mfma<2><<<dim3((H / 128) * (N / 128), 1), blk, 0, stream>>>(
        Gb, w2b, H / 128, N, H, D, D, nullptr, nullptr, Tf,
        nullptr, nullptr, dAT, gb1, 0.f);

    // gw2' = T^T @ G'  [H,D]: A=TT[H,N], Bt=GT[D,N], split-K, atomics
    const int SPLIT = 16;
    k_mfma<3><<<dim3((D / 128) * (H / 128), SPLIT), blk, 0, stream>>>(
        TT, GT, D / 128, H, D, N, N / SPLIT, nullptr, nullptr, nullptr,
        gw2, nullptr, nullptr, nullptr, 0.f);

    // gw1' = x^T @ dA'  [D,H]: A=xT[D,N], Bt=dAT[H,N]
    k_mfma<3><<<dim3((H / 128) * (D / 128), SPLIT), blk, 0, stream>>>(
        xT, dAT, H / 128, D, H, N, N / SPLIT, nullptr, nullptr, nullptr,
        gw1, nullptr, nullptr, nullptr, 0.f);

    // merged learned-optimizer update
    int nAll = D * H + H + H * D + D;
    k_update_all<<<dim3((nAll + NTHREADS - 1) / NTHREADS), blk, 0, stream>>>(
        w1, b1, w2, b2, gw1, o_w1, D * H, H, H * D, D,
        Wm1, bm1, Wm2, bm2, M, INV_SCALE_G);
}